// Round 1
// 255.869 us; speedup vs baseline: 1.0230x; 1.0230x over previous
//
#include <hip/hip_runtime.h>
#include <hip/hip_bf16.h>
#include <hip/hip_fp16.h>

#define HCONC 128   // H*C
#define NHEAD 4
#define CCH   32
#define EDIM  8
#define NREL  16
#define BCAP  5120  // per-bucket capacity (mean ~4081, +16 sigma headroom)
#define TILE  2048  // edges per binA block

typedef float floatx2 __attribute__((ext_vector_type(2)));
typedef short bf16x8 __attribute__((ext_vector_type(8)));
typedef float f32x4 __attribute__((ext_vector_type(4)));

__device__ inline unsigned short pack_fp8x2(float a, float b) {
    return (unsigned short)(__builtin_amdgcn_cvt_pk_fp8_f32(a, b, 0, false) & 0xFFFF);
}
__device__ inline unsigned pack_bf2(float lo, float hi) {
    __hip_bfloat162 v;
    v.x = __float2bfloat16(lo);
    v.y = __float2bfloat16(hi);
    return *(unsigned*)&v;
}

// ---------------------------------------------------------------------------
// binA: tile-local counting sort by dst-bucket, coalesced run writes.
// Blocks [nA, nA+92): MFMA weight packing (formerly initpack).
// Block nA+92: setup (W0s, SA0/SD0, per-type stab for all 3 layers).
// Cursors are RELATIVE (zero-initialized by a tiny memset before launch).
// ebuf record: src(16) | typ(4)<<16 | (dst&255)<<20  -- bucket implicit.
__global__ __launch_bounds__(256) void binA_kernel(
    const int* __restrict__ ei, const int* __restrict__ etype, int E, int nbuk, int nA,
    int* __restrict__ gcursor, int* __restrict__ cnt, unsigned* __restrict__ ebuf,
    const float* __restrict__ W_l1, const float* __restrict__ W_l2,
    const float* __restrict__ mW1,
    unsigned* __restrict__ Wl1q, unsigned* __restrict__ Wl2q, unsigned* __restrict__ W1q,
    const float* __restrict__ W_l0, const float* __restrict__ emb,
    const float* __restrict__ att_src, const float* __restrict__ att_dst,
    const float* __restrict__ att_edge, const float* __restrict__ W_edge,
    float* __restrict__ W0s, float* __restrict__ SA0, float* __restrict__ SD0,
    float* __restrict__ stab) {
    __shared__ int hist[256], lbase[256], gbase[256], tmp[256];
    __shared__ int lcnt16[NREL];
    __shared__ unsigned srt[TILE];
    __shared__ unsigned char sbuk[TILE];
    __shared__ float W0s_s[HCONC];
    int t = threadIdx.x;

    if ((int)blockIdx.x >= nA) {               // ---- pack / setup blocks ----
        int pb = (int)blockIdx.x - nA;
        if (pb == 92) {                        // setup (weights only; no cnt dep)
            if (t < HCONC) {
                float s = 0.f;
                for (int k = 0; k < CCH; k++) s += W_l0[k * HCONC + t];
                W0s[t] = s; W0s_s[t] = s;
            }
            __syncthreads();
            if (t < NHEAD) {
                float sa = 0.f, sd = 0.f;
                for (int c = 0; c < CCH; c++) {
                    sa += W0s_s[t * CCH + c] * att_src[t * CCH + c];
                    sd += W0s_s[t * CCH + c] * att_dst[t * CCH + c];
                }
                SA0[t] = sa; SD0[t] = sd;
            }
            if (t < 192) {                     // 3 layers x 16 types x 4 heads
                int l = t >> 6, rem = t & 63, typ = rem >> 2, hh = rem & 3;
                const float* attr = emb + typ * EDIM;
                const float* We = W_edge + l * EDIM * HCONC;
                const float* ae = att_edge + l * HCONC + hh * CCH;
                float s = 0.f;
                for (int c = 0; c < CCH; c++) {
                    float ev = 0.f;
                    for (int dd = 0; dd < EDIM; dd++)
                        ev += attr[dd] * We[dd * HCONC + hh * CCH + c];
                    s += ev * ae[c];
                }
                stab[l * 68 + typ * 4 + hh] = s;   // mean entries filled by binB b==0
            }
            return;
        }
        int i = pb * 256 + t;
        if (i < 16384) {                       // MFMA B-pack (W_l1 then W_l2)
            const float* W = (i < 8192) ? W_l1 : W_l2;
            unsigned* dst = (i < 8192) ? Wl1q : Wl2q;
            int r = i & 8191;
            int j2 = r & 3, lane = (r >> 2) & 63, kb = (r >> 8) & 3, tt = r >> 10;
            int k0 = kb * 32 + ((lane >> 4) & 3) * 8 + 2 * j2;
            int c = 16 * tt + (lane & 15);
            dst[r] = pack_bf2(W[k0 * 128 + c], W[(k0 + 1) * 128 + c]);
        } else if (i < 16384 + 7168) {         // mlp W1 B-pack, 7 tiles
            int r = i - 16384;
            int j2 = r & 3, lane = (r >> 2) & 63, kb = (r >> 8) & 3, tt = r >> 10;
            int k0 = kb * 32 + ((lane >> 4) & 3) * 8 + 2 * j2;
            int c = 16 * tt + (lane & 15);
            float lo = (c < 100) ? mW1[k0 * 100 + c] : 0.f;
            float hi = (c < 100) ? mW1[(k0 + 1) * 100 + c] : 0.f;
            W1q[r] = pack_bf2(lo, hi);
        }
        return;
    }

    // ---- edge binning ----
    hist[t] = 0;
    if (t < NREL) lcnt16[t] = 0;
    __syncthreads();

    int base = blockIdx.x * TILE;
    int count = min(TILE, E - base);

    unsigned rec[8]; int slot[8]; int buk[8];
#pragma unroll
    for (int i = 0; i < 8; i++) {
        int idx = t + i * 256;
        if (idx < count) {
            int g = base + idx;
            int s = ei[g], d = ei[E + g], ty = etype[g];
            rec[i] = (unsigned)s | ((unsigned)ty << 16) | ((unsigned)(d & 255) << 20);
            buk[i] = d >> 8;
            slot[i] = atomicAdd(&hist[buk[i]], 1);
            atomicAdd(&lcnt16[ty], 1);
        } else buk[i] = -1;
    }
    __syncthreads();

    int v = hist[t];
    tmp[t] = v; __syncthreads();
    for (int off = 1; off < 256; off <<= 1) {
        int add = (t >= off) ? tmp[t - off] : 0; __syncthreads();
        tmp[t] += add; __syncthreads();
    }
    lbase[t] = tmp[t] - v;
    if (t < nbuk && v > 0) gbase[t] = atomicAdd(&gcursor[t], v);  // relative reserve
    __syncthreads();

#pragma unroll
    for (int i = 0; i < 8; i++)
        if (buk[i] >= 0) {
            int pos = lbase[buk[i]] + slot[i];
            srt[pos] = rec[i];
            sbuk[pos] = (unsigned char)buk[i];
        }
    if (t < NREL) atomicAdd(&cnt[t], lcnt16[t]);
    __syncthreads();

    for (int idx = t; idx < count; idx += 256) {
        unsigned r = srt[idx];
        int bk = sbuk[idx];
        int rel = gbase[bk] + idx - lbase[bk];
        if (rel < BCAP) ebuf[bk * BCAP + rel] = r;   // cap guard (never trips)
    }
}

// ---------------------------------------------------------------------------
// binB: per-bucket fine sort + FUSED layer-0 aggregation.  col list stays in
// LDS (colsl) so the layer-0 pass needs no global col/row_ptr reads.  Block 0
// also materializes the cnt-weighted mean stab entries for layers 1/2 (linear
// in cnt: stab_mean = sum_r cnt[r]*stab[r]/E).
__global__ __launch_bounds__(256) void binB_kernel(
    const unsigned* __restrict__ ebuf, const int* __restrict__ gcursor,
    int n, int nbuk,
    int* __restrict__ row_ptr, unsigned* __restrict__ col,
    const int* __restrict__ cnt, float* __restrict__ stab, int E,
    const float* __restrict__ x, const float* __restrict__ W0s,
    const float* __restrict__ SA0, const float* __restrict__ SD0,
    const float* __restrict__ bias0, float* __restrict__ x_out) {
    __shared__ int hist[256], lcur[256], tmp[256];
    __shared__ unsigned colsl[BCAP];            // 20 KB
    __shared__ __align__(16) float stab0[68];
    __shared__ float val[256][4];               // 4 KB staging for epilogue
    int b = blockIdx.x, t = threadIdx.x;

    if (t < 64) stab0[t] = stab[t];             // layer-0 per-type entries
    float invE = 1.f / (float)E;
    if (t < 4) {                                // local layer-0 mean entry
        float s = 0.f;
        for (int r = 0; r < NREL; r++) s += (float)cnt[r] * stab[r * 4 + t];
        stab0[64 + t] = s * invE;
    }

    // inline bucket-base scan (gcursor holds per-bucket sizes now)
    int c = (t < nbuk) ? gcursor[t] : 0;
    tmp[t] = c; __syncthreads();
    for (int off = 1; off < 256; off <<= 1) {
        int add = (t >= off) ? tmp[t - off] : 0; __syncthreads();
        tmp[t] += add; __syncthreads();
    }
    int gstart = (b == 0) ? 0 : tmp[b - 1];
    if (b == 0 && t == nbuk - 1) row_ptr[n] = tmp[t];   // total edge count
    if (b == 0 && t < 12) {                     // global mean entries, layers 0-2
        int l = t >> 2, hh = t & 3;
        float s = 0.f;
        for (int r = 0; r < NREL; r++) s += (float)cnt[r] * stab[l * 68 + r * 4 + hh];
        stab[l * 68 + 64 + hh] = s * invE;
    }
    __syncthreads();

    int bbase = b * BCAP;
    int cntb = min(gcursor[b], BCAP);
    hist[t] = 0;
    __syncthreads();
    for (int i = t; i < cntb; i += 256) {
        unsigned r = ebuf[bbase + i];
        atomicAdd(&hist[r >> 20], 1);
    }
    __syncthreads();
    int v = hist[t];
    tmp[t] = v; __syncthreads();
    for (int off = 1; off < 256; off <<= 1) {
        int add = (t >= off) ? tmp[t - off] : 0; __syncthreads();
        tmp[t] += add; __syncthreads();
    }
    lcur[t] = tmp[t] - v;
    int gdst = (b << 8) + t;
    if (gdst < n) row_ptr[gdst] = gstart + tmp[t] - v;
    __syncthreads();
    for (int i = t; i < cntb; i += 256) {
        unsigned r = ebuf[bbase + i];
        int pos = atomicAdd(&lcur[r >> 20], 1);
        colsl[pos] = r & 0xFFFFFu;              // src | typ<<16
    }
    __syncthreads();
    for (int i = t; i < cntb; i += 256)
        col[gstart + i] = colsl[i];

    // ---- fused layer-0 aggregation (h0 is rank-1: per-(dst,head) scalar) ----
    int lo = tmp[t] - v, hi = tmp[t];           // this dst's range in colsl
    if (gdst < n) {
        float xd = x[gdst];
        float4 sa4 = *(const float4*)SA0;
        float4 sdc = *(const float4*)SD0;
        float sd0 = xd * sdc.x, sd1 = xd * sdc.y, sd2 = xd * sdc.z, sd3 = xd * sdc.w;
        // self edge (typ=16 -> mean attr)
        float s0 = fmaf(xd, sa4.x, sd0) + stab0[64];
        float s1 = fmaf(xd, sa4.y, sd1) + stab0[65];
        float s2 = fmaf(xd, sa4.z, sd2) + stab0[66];
        float s3 = fmaf(xd, sa4.w, sd3) + stab0[67];
        s0 = s0 > 0.f ? s0 : 0.2f * s0;
        s1 = s1 > 0.f ? s1 : 0.2f * s1;
        s2 = s2 > 0.f ? s2 : 0.2f * s2;
        s3 = s3 > 0.f ? s3 : 0.2f * s3;
        float w0 = __expf(s0), w1 = __expf(s1), w2 = __expf(s2), w3 = __expf(s3);
        float den0 = w0, den1 = w1, den2 = w2, den3 = w3;
        float sx0 = w0 * xd, sx1 = w1 * xd, sx2 = w2 * xd, sx3 = w3 * xd;
        for (int j = lo; j < hi; j++) {
            unsigned p = colsl[j];
            float xv = x[p & 0xFFFFu];
            int typ = (int)(p >> 16);
            float4 st = *(const float4*)&stab0[typ * 4];
            float e0 = fmaf(xv, sa4.x, sd0) + st.x;
            float e1 = fmaf(xv, sa4.y, sd1) + st.y;
            float e2 = fmaf(xv, sa4.z, sd2) + st.z;
            float e3 = fmaf(xv, sa4.w, sd3) + st.w;
            e0 = e0 > 0.f ? e0 : 0.2f * e0;
            e1 = e1 > 0.f ? e1 : 0.2f * e1;
            e2 = e2 > 0.f ? e2 : 0.2f * e2;
            e3 = e3 > 0.f ? e3 : 0.2f * e3;
            float g0 = __expf(e0), g1 = __expf(e1), g2 = __expf(e2), g3 = __expf(e3);
            den0 += g0; den1 += g1; den2 += g2; den3 += g3;
            sx0 = fmaf(g0, xv, sx0); sx1 = fmaf(g1, xv, sx1);
            sx2 = fmaf(g2, xv, sx2); sx3 = fmaf(g3, xv, sx3);
        }
        val[t][0] = sx0 / (den0 + 1e-16f);
        val[t][1] = sx1 / (den1 + 1e-16f);
        val[t][2] = sx2 / (den2 + 1e-16f);
        val[t][3] = sx3 / (den3 + 1e-16f);
    }
    __syncthreads();

    // coalesced epilogue: 32 thr/row x 8 rows per iter, out = relu(val*W0s+b)
    int cg = t & 31;                            // channel-group (4 channels)
    int hh = cg >> 3;
    float4 w4v = ((const float4*)W0s)[cg];
    float4 b4v = ((const float4*)bias0)[cg];
    for (int rb = 0; rb < 32; rb++) {
        int r = rb * 8 + (t >> 5);
        int d2 = (b << 8) + r;
        if (d2 < n) {
            float vv = val[r][hh];
            float4 o;
            o.x = fmaxf(fmaf(vv, w4v.x, b4v.x), 0.f);
            o.y = fmaxf(fmaf(vv, w4v.y, b4v.y), 0.f);
            o.z = fmaxf(fmaf(vv, w4v.z, b4v.z), 0.f);
            o.w = fmaxf(fmaf(vv, w4v.w, b4v.w), 0.f);
            ((float4*)x_out)[(size_t)d2 * 32 + cg] = o;
        }
    }
}

// ---------------------------------------------------------------------------
// Dense transform via MFMA (v_mfma_f32_16x16x32_bf16), 16-row strip per wave.
__global__ __launch_bounds__(256, 2) void transform_kernel(
    const float* __restrict__ X, const unsigned* __restrict__ Wq,
    const float* __restrict__ a_src, const float* __restrict__ a_dst,
    unsigned short* __restrict__ h8, float* __restrict__ s_src,
    float* __restrict__ s_dst, int n) {
    __shared__ unsigned short hs[64 * 128];   // 16 KB epilogue transpose
    int tid = threadIdx.x;
    int lane = tid & 63;
    int wv = tid >> 6;
    int q = lane >> 4, nl = lane & 15;
    int row_blk = blockIdx.x * 64;
    int wrow = wv * 16;

    int arow = row_blk + wrow + nl;
    if (arow >= n) arow = n - 1;              // clamp; stores are guarded
    const float4* Xr = (const float4*)(X + (size_t)arow * HCONC);

    f32x4 acc[8];
#pragma unroll
    for (int t = 0; t < 8; t++) acc[t] = (f32x4){0.f, 0.f, 0.f, 0.f};

    const uint4* Wp4 = (const uint4*)Wq;
#pragma unroll
    for (int kb = 0; kb < 4; kb++) {
        float4 xa = Xr[kb * 8 + q * 2];
        float4 xb = Xr[kb * 8 + q * 2 + 1];
        uint4 ua;
        ua.x = pack_bf2(xa.x, xa.y);
        ua.y = pack_bf2(xa.z, xa.w);
        ua.z = pack_bf2(xb.x, xb.y);
        ua.w = pack_bf2(xb.z, xb.w);
        bf16x8 af = __builtin_bit_cast(bf16x8, ua);
#pragma unroll
        for (int t = 0; t < 8; t++) {
            uint4 ub = Wp4[(t * 4 + kb) * 64 + lane];
            bf16x8 bf = __builtin_bit_cast(bf16x8, ub);
            acc[t] = __builtin_amdgcn_mfma_f32_16x16x32_bf16(af, bf, acc[t], 0, 0, 0);
        }
    }

    // scores: lane holds col c=16t+nl of rows wrow+q*4+reg
    float av[8], dv[8];
#pragma unroll
    for (int t = 0; t < 8; t++) {
        av[t] = a_src[16 * t + nl];
        dv[t] = a_dst[16 * t + nl];
    }
#pragma unroll
    for (int reg = 0; reg < 4; reg++) {
        float t0 = acc[0][reg] * av[0] + acc[1][reg] * av[1];
        float t1 = acc[2][reg] * av[2] + acc[3][reg] * av[3];
        float t2 = acc[4][reg] * av[4] + acc[5][reg] * av[5];
        float t3 = acc[6][reg] * av[6] + acc[7][reg] * av[7];
        float d0 = acc[0][reg] * dv[0] + acc[1][reg] * dv[1];
        float d1 = acc[2][reg] * dv[2] + acc[3][reg] * dv[3];
        float d2 = acc[4][reg] * dv[4] + acc[5][reg] * dv[5];
        float d3 = acc[6][reg] * dv[6] + acc[7][reg] * dv[7];
#pragma unroll
        for (int off = 1; off <= 8; off <<= 1) {
            t0 += __shfl_xor(t0, off); t1 += __shfl_xor(t1, off);
            t2 += __shfl_xor(t2, off); t3 += __shfl_xor(t3, off);
            d0 += __shfl_xor(d0, off); d1 += __shfl_xor(d1, off);
            d2 += __shfl_xor(d2, off); d3 += __shfl_xor(d3, off);
        }
        int row = row_blk + wrow + q * 4 + reg;
        if (row < n && nl < 4) {
            float ts = nl == 0 ? t0 : nl == 1 ? t1 : nl == 2 ? t2 : t3;
            float td = nl == 0 ? d0 : nl == 1 ? d1 : nl == 2 ? d2 : d3;
            s_src[row * 4 + nl] = ts;
            s_dst[row * 4 + nl] = td;
        }
    }

    // h8: transpose acc through LDS (bf16) then pack fp8 coalesced
#pragma unroll
    for (int t = 0; t < 8; t++) {
#pragma unroll
        for (int reg = 0; reg < 4; reg++) {
            __hip_bfloat16 b = __float2bfloat16(acc[t][reg]);
            hs[(wrow + q * 4 + reg) * 128 + 16 * t + nl] = *(unsigned short*)&b;
        }
    }
    __syncthreads();
    const unsigned* hsu = (const unsigned*)hs;
#pragma unroll
    for (int i = 0; i < 16; i++) {
        int pidx = tid + i * 256;             // channel-pair index in 64x64
        int rl = pidx >> 6, cp = pidx & 63;
        int row = row_blk + rl;
        if (row < n) {
            unsigned u = hsu[rl * 64 + cp];
            float f0 = __uint_as_float(u << 16);
            float f1 = __uint_as_float(u & 0xFFFF0000u);
            h8[(size_t)row * 64 + cp] = pack_fp8x2(f0, f1);
        }
    }
}

// ---------------------------------------------------------------------------
// Softmax-aggregation v2: chunked score phase (each lane computes ONE edge's
// 4 head-weights — 4 exps/edge, one float4 s_src load/edge) +
// shuffle-broadcast inner loop (register exchange, no extra gathers).
// 4 streams x 16 lanes; lane owns 8 fp8 channels; self-loop analytic.
__global__ __launch_bounds__(256) void agg_kernel(
    const unsigned char* __restrict__ h8,   // fp8 e4m3, [n][128]
    const float* __restrict__ s_src, const float* __restrict__ s_dst,
    const int* __restrict__ row_ptr, const unsigned* __restrict__ col,
    const float* __restrict__ tab, const float* __restrict__ bias,
    const float* __restrict__ x_prev, float* __restrict__ x_out, int n) {
    __shared__ __align__(16) float stab_s[68];
    if (threadIdx.x < 68) stab_s[threadIdx.x] = tab[threadIdx.x];
    __syncthreads();

    int d = __builtin_amdgcn_readfirstlane(blockIdx.x * 4 + (threadIdx.x >> 6));
    if (d >= n) return;
    int lane = threadIdx.x & 63;
    int strm = lane >> 4;             // 0..3
    int l16 = lane & 15;              // channel group within row
    int head = l16 >> 2;              // 4 lanes/head

    int start = row_ptr[d], end = row_ptr[d + 1];
    float4 sd4 = ((const float4*)s_dst)[d];

    float den = 0.f;
    float a0 = 0.f, a1 = 0.f, a2 = 0.f, a3 = 0.f;
    float a4 = 0.f, a5 = 0.f, a6 = 0.f, a7 = 0.f;

    if (strm == 0) {                  // self edge (typ=16, mean attr)
        float sdh = head == 0 ? sd4.x : head == 1 ? sd4.y : head == 2 ? sd4.z : sd4.w;
        float s = s_src[d * 4 + head] + sdh + stab_s[64 + head];
        s = s > 0.f ? s : 0.2f * s;
        float w = __expf(s);
        uint2 u = ((const uint2*)(h8 + (size_t)d * 128))[l16];
        floatx2 f01 = __builtin_amdgcn_cvt_pk_f32_fp8((int)u.x, false);
        floatx2 f23 = __builtin_amdgcn_cvt_pk_f32_fp8((int)u.x, true);
        floatx2 f45 = __builtin_amdgcn_cvt_pk_f32_fp8((int)u.y, false);
        floatx2 f67 = __builtin_amdgcn_cvt_pk_f32_fp8((int)u.y, true);
        den = w;
        a0 = w * f01.x;  a1 = w * f01.y;
        a2 = w * f23.x;  a3 = w * f23.y;
        a4 = w * f45.x;  a5 = w * f45.y;
        a6 = w * f67.x;  a7 = w * f67.y;
    }

    for (int base = start; base < end; base += 64) {
        // score phase: lane computes edge base+lane's 4 head-weights
        float4 w4 = make_float4(0.f, 0.f, 0.f, 0.f);
        int esrc = 0;
        int e = base + lane;
        if (e < end) {
            unsigned pp = col[e];
            esrc = (int)(pp & 0xFFFFu);
            int typ = (int)(pp >> 16);
            float4 ss4 = ((const float4*)s_src)[esrc];
            float4 st4 = *(const float4*)&stab_s[typ * 4];
            float s0 = ss4.x + sd4.x + st4.x;
            float s1 = ss4.y + sd4.y + st4.y;
            float s2 = ss4.z + sd4.z + st4.z;
            float s3 = ss4.w + sd4.w + st4.w;
            s0 = s0 > 0.f ? s0 : 0.2f * s0;
            s1 = s1 > 0.f ? s1 : 0.2f * s1;
            s2 = s2 > 0.f ? s2 : 0.2f * s2;
            s3 = s3 > 0.f ? s3 : 0.2f * s3;
            w4.x = __expf(s0); w4.y = __expf(s1);
            w4.z = __expf(s2); w4.w = __expf(s3);
        }
        int C = min(64, end - base);
        int steps = (C + 3) >> 2;
        for (int i = 0; i < steps; i++) {
            int j = i * 4 + strm;             // padding lanes carry w4 = 0
            float wx = __shfl(w4.x, j);
            float wy = __shfl(w4.y, j);
            float wz = __shfl(w4.z, j);
            float ww = __shfl(w4.w, j);
            int sj = __shfl(esrc, j);
            float w = head == 0 ? wx : head == 1 ? wy : head == 2 ? wz : ww;
            uint2 u = ((const uint2*)(h8 + (size_t)sj * 128))[l16];
            floatx2 f01 = __builtin_amdgcn_cvt_pk_f32_fp8((int)u.x, false);
            floatx2 f23 = __builtin_amdgcn_cvt_pk_f32_fp8((int)u.x, true);
            floatx2 f45 = __builtin_amdgcn_cvt_pk_f32_fp8((int)u.y, false);
            floatx2 f67 = __builtin_amdgcn_cvt_pk_f32_fp8((int)u.y, true);
            den += w;
            a0 = fmaf(w, f01.x, a0);  a1 = fmaf(w, f01.y, a1);
            a2 = fmaf(w, f23.x, a2);  a3 = fmaf(w, f23.y, a3);
            a4 = fmaf(w, f45.x, a4);  a5 = fmaf(w, f45.y, a5);
            a6 = fmaf(w, f67.x, a6);  a7 = fmaf(w, f67.y, a7);
        }
    }

    // merge 4 streams: plain sums, xor16 then xor32
#pragma unroll
    for (int off = 16; off <= 32; off <<= 1) {
        den += __shfl_xor(den, off);
        a0 += __shfl_xor(a0, off);  a1 += __shfl_xor(a1, off);
        a2 += __shfl_xor(a2, off);  a3 += __shfl_xor(a3, off);
        a4 += __shfl_xor(a4, off);  a5 += __shfl_xor(a5, off);
        a6 += __shfl_xor(a6, off);  a7 += __shfl_xor(a7, off);
    }

    if (lane < 16) {
        float inv = 1.f / (den + 1e-16f);
        float4 b0 = ((const float4*)bias)[2 * l16];
        float4 b1v = ((const float4*)bias)[2 * l16 + 1];
        float4 o0v, o1v;
        o0v.x = a0 * inv + b0.x;  o0v.y = a1 * inv + b0.y;
        o0v.z = a2 * inv + b0.z;  o0v.w = a3 * inv + b0.w;
        o1v.x = a4 * inv + b1v.x; o1v.y = a5 * inv + b1v.y;
        o1v.z = a6 * inv + b1v.z; o1v.w = a7 * inv + b1v.w;
        if (x_prev) {
            float4 p0 = ((const float4*)x_prev)[(size_t)d * 32 + 2 * l16];
            float4 p1 = ((const float4*)x_prev)[(size_t)d * 32 + 2 * l16 + 1];
            o0v.x += p0.x; o0v.y += p0.y; o0v.z += p0.z; o0v.w += p0.w;
            o1v.x += p1.x; o1v.y += p1.y; o1v.z += p1.z; o1v.w += p1.w;
        }
        o0v.x = fmaxf(o0v.x, 0.f); o0v.y = fmaxf(o0v.y, 0.f);
        o0v.z = fmaxf(o0v.z, 0.f); o0v.w = fmaxf(o0v.w, 0.f);
        o1v.x = fmaxf(o1v.x, 0.f); o1v.y = fmaxf(o1v.y, 0.f);
        o1v.z = fmaxf(o1v.z, 0.f); o1v.w = fmaxf(o1v.w, 0.f);
        ((float4*)x_out)[(size_t)d * 32 + 2 * l16]     = o0v;
        ((float4*)x_out)[(size_t)d * 32 + 2 * l16 + 1] = o1v;
    }
}

// ---------------------------------------------------------------------------
// MLP head via MFMA: 7 col-tiles (hidden 0..111, >=100 zero-padded in pack).
__global__ __launch_bounds__(256, 2) void mlp_kernel(
    const float* __restrict__ X, const unsigned* __restrict__ W1q,
    const float* __restrict__ b1, const float* __restrict__ W2,
    const float* __restrict__ b2, float* __restrict__ out, int n) {
    int tid = threadIdx.x;
    int lane = tid & 63;
    int wv = tid >> 6;
    int q = lane >> 4, nl = lane & 15;
    int row_blk = blockIdx.x * 64;
    int wrow = wv * 16;

    int arow = row_blk + wrow + nl;
    if (arow >= n) arow = n - 1;
    const float4* Xr = (const float4*)(X + (size_t)arow * HCONC);

    f32x4 acc[7];
#pragma unroll
    for (int t = 0; t < 7; t++) acc[t] = (f32x4){0.f, 0.f, 0.f, 0.f};

    const uint4* Wp4 = (const uint4*)W1q;
#pragma unroll
    for (int kb = 0; kb < 4; kb++) {
        float4 xa = Xr[kb * 8 + q * 2];
        float4 xb = Xr[kb * 8 + q * 2 + 1];
        uint4 ua;
        ua.x = pack_bf2(xa.x, xa.y);
        ua.y = pack_bf2(xa.z, xa.w);
        ua.z = pack_bf2(xb.x, xb.y);
        ua.w = pack_bf2(xb.z, xb.w);
        bf16x8 af = __builtin_bit_cast(bf16x8, ua);
#pragma unroll
        for (int t = 0; t < 7; t++) {
            uint4 ub = Wp4[(t * 4 + kb) * 64 + lane];
            bf16x8 bf = __builtin_bit_cast(bf16x8, ub);
            acc[t] = __builtin_amdgcn_mfma_f32_16x16x32_bf16(af, bf, acc[t], 0, 0, 0);
        }
    }

    float b1c[7], w2c[7];
#pragma unroll
    for (int t = 0; t < 7; t++) {
        int c = 16 * t + nl;
        bool vld = c < 100;
        b1c[t] = vld ? b1[c] : 0.f;
        w2c[t] = vld ? W2[c] : 0.f;
    }
    float b2v = b2[0];

#pragma unroll
    for (int reg = 0; reg < 4; reg++) {
        float sum = 0.f;
#pragma unroll
        for (int t = 0; t < 7; t++) {
            float hv = fmaxf(acc[t][reg] + b1c[t], 0.f);
            sum = fmaf(hv, w2c[t], sum);
        }
#pragma unroll
        for (int off = 1; off <= 8; off <<= 1)
            sum += __shfl_xor(sum, off);
        int row = row_blk + wrow + q * 4 + reg;
        if (nl == 0 && row < n)
            out[row] = 1.f / (1.f + __expf(-(sum + b2v)));
    }
}

// ---------------------------------------------------------------------------
extern "C" void kernel_launch(void* const* d_in, const int* in_sizes, int n_in,
                              void* d_out, int out_size, void* d_ws, size_t ws_size,
                              hipStream_t stream) {
    const float* x       = (const float*)d_in[0];
    const int*   ei      = (const int*)d_in[1];     // [2,E]: src then dst
    const int*   etype   = (const int*)d_in[2];
    const float* emb     = (const float*)d_in[3];   // [16,8]
    const float* W_l0    = (const float*)d_in[4];   // [32,128]
    const float* W_l1    = (const float*)d_in[5];   // [128,128]
    const float* W_l2    = (const float*)d_in[6];   // [128,128]
    const float* att_src = (const float*)d_in[7];   // [3,4,32]
    const float* att_dst = (const float*)d_in[8];
    const float* att_edge= (const float*)d_in[9];
    const float* W_edge  = (const float*)d_in[10];  // [3,8,128]
    const float* bias    = (const float*)d_in[11];  // [3,128]
    const float* mW1     = (const float*)d_in[12];  // [128,100]
    const float* mb1     = (const float*)d_in[13];
    const float* mW2     = (const float*)d_in[14];  // [100,1]
    const float* mb2     = (const float*)d_in[15];

    int n = in_sizes[0];   // 50000
    int E = in_sizes[2];   // 800000
    int nbuk = (n + 255) >> 8;   // 196
    int nA = (E + TILE - 1) / TILE;   // 391

    // workspace carve (keep 16-byte alignment for uint4 views)
    float* p   = (float*)d_ws;
    float* xa  = p; p += (size_t)n * HCONC;
    float* xb  = p; p += (size_t)n * HCONC;
    float* ssrc = p; p += (size_t)n * NHEAD;
    float* sdst = p; p += (size_t)n * NHEAD;
    float* hbf  = p; p += (size_t)n * 32;          // fp8 h buffer (n*128 bytes)
    unsigned* Wl1q = (unsigned*)p; p += 8192;      // MFMA-B-packed W_l1
    unsigned* Wl2q = (unsigned*)p; p += 8192;      // MFMA-B-packed W_l2
    unsigned* W1q  = (unsigned*)p; p += 7168;      // MFMA-B-packed mW1 (7 tiles)
    int* row_ptr     = (int*)p;
    int* gcursor     = row_ptr + n + 1;
    int* cnt         = gcursor + 256;
    float* W0s    = (float*)(cnt + 16);
    float* SA0    = W0s + HCONC;
    float* SD0    = SA0 + NHEAD;
    float* meanat = SD0 + NHEAD;     // unused (kept for layout stability)
    float* stab   = meanat + EDIM;   // 3*68 = 204, round to 256
    char* raw = (char*)(stab + 256);
    unsigned* ebuf = (unsigned*)(((uintptr_t)raw + 15) & ~(uintptr_t)15); // nbuk*BCAP u32
    unsigned* col = ebuf + (size_t)nbuk * BCAP;                          // E entries

    // CSR build: memset cursors -> binA (binning + weight pack + setup riding
    // along) -> binB (fine sort + fused layer-0 aggregation)
    hipMemsetAsync(gcursor, 0, (256 + 16) * sizeof(int), stream);
    binA_kernel<<<nA + 93, 256, 0, stream>>>(ei, etype, E, nbuk, nA, gcursor, cnt,
                                             ebuf, W_l1, W_l2, mW1, Wl1q, Wl2q, W1q,
                                             W_l0, emb, att_src, att_dst, att_edge,
                                             W_edge, W0s, SA0, SD0, stab);
    binB_kernel<<<nbuk, 256, 0, stream>>>(ebuf, gcursor, n, nbuk, row_ptr, col,
                                          cnt, stab, E, x, W0s, SA0, SD0,
                                          bias + 0, xa);

    // layer 1
    transform_kernel<<<(n + 63) / 64, 256, 0, stream>>>(xa, Wl1q, att_src + 128, att_dst + 128,
                                                        (unsigned short*)hbf, ssrc, sdst, n);
    agg_kernel<<<(n + 3) / 4, 256, 0, stream>>>((const unsigned char*)hbf, ssrc, sdst, row_ptr, col,
                                                stab + 68, bias + 128, xa, xb, n);
    // layer 2
    transform_kernel<<<(n + 63) / 64, 256, 0, stream>>>(xb, Wl2q, att_src + 256, att_dst + 256,
                                                        (unsigned short*)hbf, ssrc, sdst, n);
    agg_kernel<<<(n + 3) / 4, 256, 0, stream>>>((const unsigned char*)hbf, ssrc, sdst, row_ptr, col,
                                                stab + 136, bias + 256, xb, xa, n);
    // MLP head (MFMA)
    mlp_kernel<<<(n + 63) / 64, 256, 0, stream>>>(xa, W1q, mb1, mW2, mb2, (float*)d_out, n);
}

// Round 2
// 246.851 us; speedup vs baseline: 1.0603x; 1.0365x over previous
//
#include <hip/hip_runtime.h>
#include <hip/hip_bf16.h>
#include <hip/hip_fp16.h>

#define HCONC 128   // H*C
#define NHEAD 4
#define CCH   32
#define EDIM  8
#define NREL  16
#define BCAP  5120  // per-bucket capacity (mean ~4081, +16 sigma headroom)
#define TILE  2048  // edges per binA block

typedef float floatx2 __attribute__((ext_vector_type(2)));
typedef short bf16x8 __attribute__((ext_vector_type(8)));
typedef float f32x4 __attribute__((ext_vector_type(4)));

__device__ inline unsigned short pack_fp8x2(float a, float b) {
    return (unsigned short)(__builtin_amdgcn_cvt_pk_fp8_f32(a, b, 0, false) & 0xFFFF);
}
__device__ inline unsigned pack_bf2(float lo, float hi) {
    __hip_bfloat162 v;
    v.x = __float2bfloat16(lo);
    v.y = __float2bfloat16(hi);
    return *(unsigned*)&v;
}

// ---------------------------------------------------------------------------
// binA: tile-local counting sort by dst-bucket, coalesced run writes.
// Blocks [nA, nA+92): MFMA weight packing.  Block nA+92: setup.
// Cursors are RELATIVE (zero-initialized by a tiny memset before launch).
// ebuf record: src(16) | typ(4)<<16 | (dst&255)<<20  -- bucket implicit.
__global__ __launch_bounds__(256) void binA_kernel(
    const int* __restrict__ ei, const int* __restrict__ etype, int E, int nbuk, int nA,
    int* __restrict__ gcursor, int* __restrict__ cnt, unsigned* __restrict__ ebuf,
    const float* __restrict__ W_l1, const float* __restrict__ W_l2,
    const float* __restrict__ mW1,
    unsigned* __restrict__ Wl1q, unsigned* __restrict__ Wl2q, unsigned* __restrict__ W1q,
    const float* __restrict__ W_l0, const float* __restrict__ emb,
    const float* __restrict__ att_src, const float* __restrict__ att_dst,
    const float* __restrict__ att_edge, const float* __restrict__ W_edge,
    float* __restrict__ W0s, float* __restrict__ SA0, float* __restrict__ SD0,
    float* __restrict__ stab) {
    __shared__ int hist[256], lbase[256], gbase[256], tmp[256];
    __shared__ int lcnt16[NREL];
    __shared__ unsigned srt[TILE];
    __shared__ unsigned char sbuk[TILE];
    __shared__ float W0s_s[HCONC];
    int t = threadIdx.x;

    if ((int)blockIdx.x >= nA) {               // ---- pack / setup blocks ----
        int pb = (int)blockIdx.x - nA;
        if (pb == 92) {                        // setup (weights only; no cnt dep)
            if (t < HCONC) {
                float s = 0.f;
                for (int k = 0; k < CCH; k++) s += W_l0[k * HCONC + t];
                W0s[t] = s; W0s_s[t] = s;
            }
            __syncthreads();
            if (t < NHEAD) {
                float sa = 0.f, sd = 0.f;
                for (int c = 0; c < CCH; c++) {
                    sa += W0s_s[t * CCH + c] * att_src[t * CCH + c];
                    sd += W0s_s[t * CCH + c] * att_dst[t * CCH + c];
                }
                SA0[t] = sa; SD0[t] = sd;
            }
            if (t < 192) {                     // 3 layers x 16 types x 4 heads
                int l = t >> 6, rem = t & 63, typ = rem >> 2, hh = rem & 3;
                const float* attr = emb + typ * EDIM;
                const float* We = W_edge + l * EDIM * HCONC;
                const float* ae = att_edge + l * HCONC + hh * CCH;
                float s = 0.f;
                for (int c = 0; c < CCH; c++) {
                    float ev = 0.f;
                    for (int dd = 0; dd < EDIM; dd++)
                        ev += attr[dd] * We[dd * HCONC + hh * CCH + c];
                    s += ev * ae[c];
                }
                stab[l * 68 + typ * 4 + hh] = s;   // mean entries filled by binB b==0
            }
            return;
        }
        int i = pb * 256 + t;
        if (i < 16384) {                       // MFMA B-pack (W_l1 then W_l2)
            const float* W = (i < 8192) ? W_l1 : W_l2;
            unsigned* dst = (i < 8192) ? Wl1q : Wl2q;
            int r = i & 8191;
            int j2 = r & 3, lane = (r >> 2) & 63, kb = (r >> 8) & 3, tt = r >> 10;
            int k0 = kb * 32 + ((lane >> 4) & 3) * 8 + 2 * j2;
            int c = 16 * tt + (lane & 15);
            dst[r] = pack_bf2(W[k0 * 128 + c], W[(k0 + 1) * 128 + c]);
        } else if (i < 16384 + 7168) {         // mlp W1 B-pack, 7 tiles
            int r = i - 16384;
            int j2 = r & 3, lane = (r >> 2) & 63, kb = (r >> 8) & 3, tt = r >> 10;
            int k0 = kb * 32 + ((lane >> 4) & 3) * 8 + 2 * j2;
            int c = 16 * tt + (lane & 15);
            float lo = (c < 100) ? mW1[k0 * 100 + c] : 0.f;
            float hi = (c < 100) ? mW1[(k0 + 1) * 100 + c] : 0.f;
            W1q[r] = pack_bf2(lo, hi);
        }
        return;
    }

    // ---- edge binning ----
    hist[t] = 0;
    if (t < NREL) lcnt16[t] = 0;
    __syncthreads();

    int base = blockIdx.x * TILE;
    int count = min(TILE, E - base);

    unsigned rec[8]; int slot[8]; int buk[8];
#pragma unroll
    for (int i = 0; i < 8; i++) {
        int idx = t + i * 256;
        if (idx < count) {
            int g = base + idx;
            int s = ei[g], d = ei[E + g], ty = etype[g];
            rec[i] = (unsigned)s | ((unsigned)ty << 16) | ((unsigned)(d & 255) << 20);
            buk[i] = d >> 8;
            slot[i] = atomicAdd(&hist[buk[i]], 1);
            atomicAdd(&lcnt16[ty], 1);
        } else buk[i] = -1;
    }
    __syncthreads();

    int v = hist[t];
    tmp[t] = v; __syncthreads();
    for (int off = 1; off < 256; off <<= 1) {
        int add = (t >= off) ? tmp[t - off] : 0; __syncthreads();
        tmp[t] += add; __syncthreads();
    }
    lbase[t] = tmp[t] - v;
    if (t < nbuk && v > 0) gbase[t] = atomicAdd(&gcursor[t], v);  // relative reserve
    __syncthreads();

#pragma unroll
    for (int i = 0; i < 8; i++)
        if (buk[i] >= 0) {
            int pos = lbase[buk[i]] + slot[i];
            srt[pos] = rec[i];
            sbuk[pos] = (unsigned char)buk[i];
        }
    if (t < NREL) atomicAdd(&cnt[t], lcnt16[t]);
    __syncthreads();

    for (int idx = t; idx < count; idx += 256) {
        unsigned r = srt[idx];
        int bk = sbuk[idx];
        int rel = gbase[bk] + idx - lbase[bk];
        if (rel < BCAP) ebuf[bk * BCAP + rel] = r;   // cap guard (never trips)
    }
}

// ---------------------------------------------------------------------------
// binB: per-bucket fine sort + FUSED layer-0 aggregation.  Layer-0 output is
// rank-1 per head, so only val[n][4] is materialized (0.8 MB instead of the
// 25.6 MB xa row buffer); downstream consumers reconstruct
// xa[d][c] = relu(val[d][c>>5]*W0s[c]+bias0[c]) bit-identically on the fly.
__global__ __launch_bounds__(256) void binB_kernel(
    const unsigned* __restrict__ ebuf, const int* __restrict__ gcursor,
    int n, int nbuk,
    int* __restrict__ row_ptr, unsigned* __restrict__ col,
    const int* __restrict__ cnt, float* __restrict__ stab, int E,
    const float* __restrict__ x,
    const float* __restrict__ SA0, const float* __restrict__ SD0,
    float* __restrict__ val0) {
    __shared__ int hist[256], lcur[256], tmp[256];
    __shared__ unsigned colsl[BCAP];            // 20 KB
    __shared__ __align__(16) float stab0[68];
    int b = blockIdx.x, t = threadIdx.x;

    if (t < 64) stab0[t] = stab[t];             // layer-0 per-type entries
    float invE = 1.f / (float)E;
    if (t < 4) {                                // local layer-0 mean entry
        float s = 0.f;
        for (int r = 0; r < NREL; r++) s += (float)cnt[r] * stab[r * 4 + t];
        stab0[64 + t] = s * invE;
    }

    // inline bucket-base scan (gcursor holds per-bucket sizes)
    int c = (t < nbuk) ? gcursor[t] : 0;
    tmp[t] = c; __syncthreads();
    for (int off = 1; off < 256; off <<= 1) {
        int add = (t >= off) ? tmp[t - off] : 0; __syncthreads();
        tmp[t] += add; __syncthreads();
    }
    int gstart = (b == 0) ? 0 : tmp[b - 1];
    if (b == 0 && t == nbuk - 1) row_ptr[n] = tmp[t];   // total edge count
    if (b == 0 && t < 12) {                     // global mean entries, layers 0-2
        int l = t >> 2, hh = t & 3;
        float s = 0.f;
        for (int r = 0; r < NREL; r++) s += (float)cnt[r] * stab[l * 68 + r * 4 + hh];
        stab[l * 68 + 64 + hh] = s * invE;
    }
    __syncthreads();

    int bbase = b * BCAP;
    int cntb = min(gcursor[b], BCAP);
    hist[t] = 0;
    __syncthreads();
    for (int i = t; i < cntb; i += 256) {
        unsigned r = ebuf[bbase + i];
        atomicAdd(&hist[r >> 20], 1);
    }
    __syncthreads();
    int v = hist[t];
    tmp[t] = v; __syncthreads();
    for (int off = 1; off < 256; off <<= 1) {
        int add = (t >= off) ? tmp[t - off] : 0; __syncthreads();
        tmp[t] += add; __syncthreads();
    }
    lcur[t] = tmp[t] - v;
    int gdst = (b << 8) + t;
    if (gdst < n) row_ptr[gdst] = gstart + tmp[t] - v;
    __syncthreads();
    for (int i = t; i < cntb; i += 256) {
        unsigned r = ebuf[bbase + i];
        int pos = atomicAdd(&lcur[r >> 20], 1);
        colsl[pos] = r & 0xFFFFFu;              // src | typ<<16
    }
    __syncthreads();
    for (int i = t; i < cntb; i += 256)
        col[gstart + i] = colsl[i];

    // ---- fused layer-0 aggregation (h0 is rank-1: per-(dst,head) scalar) ----
    int lo = tmp[t] - v, hi = tmp[t];           // this dst's range in colsl
    if (gdst < n) {
        float xd = x[gdst];
        float4 sa4 = *(const float4*)SA0;
        float4 sdc = *(const float4*)SD0;
        float sd0 = xd * sdc.x, sd1 = xd * sdc.y, sd2 = xd * sdc.z, sd3 = xd * sdc.w;
        // self edge (typ=16 -> mean attr)
        float s0 = fmaf(xd, sa4.x, sd0) + stab0[64];
        float s1 = fmaf(xd, sa4.y, sd1) + stab0[65];
        float s2 = fmaf(xd, sa4.z, sd2) + stab0[66];
        float s3 = fmaf(xd, sa4.w, sd3) + stab0[67];
        s0 = s0 > 0.f ? s0 : 0.2f * s0;
        s1 = s1 > 0.f ? s1 : 0.2f * s1;
        s2 = s2 > 0.f ? s2 : 0.2f * s2;
        s3 = s3 > 0.f ? s3 : 0.2f * s3;
        float w0 = __expf(s0), w1 = __expf(s1), w2 = __expf(s2), w3 = __expf(s3);
        float den0 = w0, den1 = w1, den2 = w2, den3 = w3;
        float sx0 = w0 * xd, sx1 = w1 * xd, sx2 = w2 * xd, sx3 = w3 * xd;
        for (int j = lo; j < hi; j++) {
            unsigned p = colsl[j];
            float xv = x[p & 0xFFFFu];
            int typ = (int)(p >> 16);
            float4 st = *(const float4*)&stab0[typ * 4];
            float e0 = fmaf(xv, sa4.x, sd0) + st.x;
            float e1 = fmaf(xv, sa4.y, sd1) + st.y;
            float e2 = fmaf(xv, sa4.z, sd2) + st.z;
            float e3 = fmaf(xv, sa4.w, sd3) + st.w;
            e0 = e0 > 0.f ? e0 : 0.2f * e0;
            e1 = e1 > 0.f ? e1 : 0.2f * e1;
            e2 = e2 > 0.f ? e2 : 0.2f * e2;
            e3 = e3 > 0.f ? e3 : 0.2f * e3;
            float g0 = __expf(e0), g1 = __expf(e1), g2 = __expf(e2), g3 = __expf(e3);
            den0 += g0; den1 += g1; den2 += g2; den3 += g3;
            sx0 = fmaf(g0, xv, sx0); sx1 = fmaf(g1, xv, sx1);
            sx2 = fmaf(g2, xv, sx2); sx3 = fmaf(g3, xv, sx3);
        }
        float4 vo;
        vo.x = sx0 / (den0 + 1e-16f);
        vo.y = sx1 / (den1 + 1e-16f);
        vo.z = sx2 / (den2 + 1e-16f);
        vo.w = sx3 / (den3 + 1e-16f);
        ((float4*)val0)[gdst] = vo;
    }
}

// ---------------------------------------------------------------------------
// Layer-1 transform: A rows reconstructed in-register from val0 (rank-1 layer-0
// output), B = MFMA-packed W_l1.  Bit-identical to reading the materialized xa.
__global__ __launch_bounds__(256, 2) void transform0_kernel(
    const float* __restrict__ val0, const float* __restrict__ W0s,
    const float* __restrict__ bias0, const unsigned* __restrict__ Wq,
    const float* __restrict__ a_src, const float* __restrict__ a_dst,
    unsigned short* __restrict__ h8, float* __restrict__ s_src,
    float* __restrict__ s_dst, int n) {
    __shared__ unsigned short hs[64 * 128];   // 16 KB epilogue transpose
    int tid = threadIdx.x;
    int lane = tid & 63;
    int wv = tid >> 6;
    int q = lane >> 4, nl = lane & 15;
    int row_blk = blockIdx.x * 64;
    int wrow = wv * 16;

    int arow = row_blk + wrow + nl;
    if (arow >= n) arow = n - 1;              // clamp; stores are guarded
    float4 v4 = ((const float4*)val0)[arow];

    f32x4 acc[8];
#pragma unroll
    for (int t = 0; t < 8; t++) acc[t] = (f32x4){0.f, 0.f, 0.f, 0.f};

    const uint4* Wp4 = (const uint4*)Wq;
#pragma unroll
    for (int kb = 0; kb < 4; kb++) {
        int c4 = 8 * kb + 2 * q;              // float4 index of channel block
        float4 wa = ((const float4*)W0s)[c4];
        float4 wb = ((const float4*)W0s)[c4 + 1];
        float4 ba = ((const float4*)bias0)[c4];
        float4 bb = ((const float4*)bias0)[c4 + 1];
        float vr = kb == 0 ? v4.x : kb == 1 ? v4.y : kb == 2 ? v4.z : v4.w;
        float x0 = fmaxf(fmaf(vr, wa.x, ba.x), 0.f);
        float x1 = fmaxf(fmaf(vr, wa.y, ba.y), 0.f);
        float x2 = fmaxf(fmaf(vr, wa.z, ba.z), 0.f);
        float x3 = fmaxf(fmaf(vr, wa.w, ba.w), 0.f);
        float x4 = fmaxf(fmaf(vr, wb.x, bb.x), 0.f);
        float x5 = fmaxf(fmaf(vr, wb.y, bb.y), 0.f);
        float x6 = fmaxf(fmaf(vr, wb.z, bb.z), 0.f);
        float x7 = fmaxf(fmaf(vr, wb.w, bb.w), 0.f);
        uint4 ua;
        ua.x = pack_bf2(x0, x1);
        ua.y = pack_bf2(x2, x3);
        ua.z = pack_bf2(x4, x5);
        ua.w = pack_bf2(x6, x7);
        bf16x8 af = __builtin_bit_cast(bf16x8, ua);
#pragma unroll
        for (int t = 0; t < 8; t++) {
            uint4 ub = Wp4[(t * 4 + kb) * 64 + lane];
            bf16x8 bf = __builtin_bit_cast(bf16x8, ub);
            acc[t] = __builtin_amdgcn_mfma_f32_16x16x32_bf16(af, bf, acc[t], 0, 0, 0);
        }
    }

    // scores: lane holds col c=16t+nl of rows wrow+q*4+reg
    float av[8], dv[8];
#pragma unroll
    for (int t = 0; t < 8; t++) {
        av[t] = a_src[16 * t + nl];
        dv[t] = a_dst[16 * t + nl];
    }
#pragma unroll
    for (int reg = 0; reg < 4; reg++) {
        float t0 = acc[0][reg] * av[0] + acc[1][reg] * av[1];
        float t1 = acc[2][reg] * av[2] + acc[3][reg] * av[3];
        float t2 = acc[4][reg] * av[4] + acc[5][reg] * av[5];
        float t3 = acc[6][reg] * av[6] + acc[7][reg] * av[7];
        float d0 = acc[0][reg] * dv[0] + acc[1][reg] * dv[1];
        float d1 = acc[2][reg] * dv[2] + acc[3][reg] * dv[3];
        float d2 = acc[4][reg] * dv[4] + acc[5][reg] * dv[5];
        float d3 = acc[6][reg] * dv[6] + acc[7][reg] * dv[7];
#pragma unroll
        for (int off = 1; off <= 8; off <<= 1) {
            t0 += __shfl_xor(t0, off); t1 += __shfl_xor(t1, off);
            t2 += __shfl_xor(t2, off); t3 += __shfl_xor(t3, off);
            d0 += __shfl_xor(d0, off); d1 += __shfl_xor(d1, off);
            d2 += __shfl_xor(d2, off); d3 += __shfl_xor(d3, off);
        }
        int row = row_blk + wrow + q * 4 + reg;
        if (row < n && nl < 4) {
            float ts = nl == 0 ? t0 : nl == 1 ? t1 : nl == 2 ? t2 : t3;
            float td = nl == 0 ? d0 : nl == 1 ? d1 : nl == 2 ? d2 : d3;
            s_src[row * 4 + nl] = ts;
            s_dst[row * 4 + nl] = td;
        }
    }

    // h8: transpose acc through LDS (bf16) then pack fp8 coalesced
#pragma unroll
    for (int t = 0; t < 8; t++) {
#pragma unroll
        for (int reg = 0; reg < 4; reg++) {
            __hip_bfloat16 b = __float2bfloat16(acc[t][reg]);
            hs[(wrow + q * 4 + reg) * 128 + 16 * t + nl] = *(unsigned short*)&b;
        }
    }
    __syncthreads();
    const unsigned* hsu = (const unsigned*)hs;
#pragma unroll
    for (int i = 0; i < 16; i++) {
        int pidx = tid + i * 256;             // channel-pair index in 64x64
        int rl = pidx >> 6, cp = pidx & 63;
        int row = row_blk + rl;
        if (row < n) {
            unsigned u = hsu[rl * 64 + cp];
            float f0 = __uint_as_float(u << 16);
            float f1 = __uint_as_float(u & 0xFFFF0000u);
            h8[(size_t)row * 64 + cp] = pack_fp8x2(f0, f1);
        }
    }
}

// ---------------------------------------------------------------------------
// Dense transform via MFMA (f32 input rows), 16-row strip per wave.
__global__ __launch_bounds__(256, 2) void transform_kernel(
    const float* __restrict__ X, const unsigned* __restrict__ Wq,
    const float* __restrict__ a_src, const float* __restrict__ a_dst,
    unsigned short* __restrict__ h8, float* __restrict__ s_src,
    float* __restrict__ s_dst, int n) {
    __shared__ unsigned short hs[64 * 128];   // 16 KB epilogue transpose
    int tid = threadIdx.x;
    int lane = tid & 63;
    int wv = tid >> 6;
    int q = lane >> 4, nl = lane & 15;
    int row_blk = blockIdx.x * 64;
    int wrow = wv * 16;

    int arow = row_blk + wrow + nl;
    if (arow >= n) arow = n - 1;              // clamp; stores are guarded
    const float4* Xr = (const float4*)(X + (size_t)arow * HCONC);

    f32x4 acc[8];
#pragma unroll
    for (int t = 0; t < 8; t++) acc[t] = (f32x4){0.f, 0.f, 0.f, 0.f};

    const uint4* Wp4 = (const uint4*)Wq;
#pragma unroll
    for (int kb = 0; kb < 4; kb++) {
        float4 xa = Xr[kb * 8 + q * 2];
        float4 xb = Xr[kb * 8 + q * 2 + 1];
        uint4 ua;
        ua.x = pack_bf2(xa.x, xa.y);
        ua.y = pack_bf2(xa.z, xa.w);
        ua.z = pack_bf2(xb.x, xb.y);
        ua.w = pack_bf2(xb.z, xb.w);
        bf16x8 af = __builtin_bit_cast(bf16x8, ua);
#pragma unroll
        for (int t = 0; t < 8; t++) {
            uint4 ub = Wp4[(t * 4 + kb) * 64 + lane];
            bf16x8 bf = __builtin_bit_cast(bf16x8, ub);
            acc[t] = __builtin_amdgcn_mfma_f32_16x16x32_bf16(af, bf, acc[t], 0, 0, 0);
        }
    }

    // scores: lane holds col c=16t+nl of rows wrow+q*4+reg
    float av[8], dv[8];
#pragma unroll
    for (int t = 0; t < 8; t++) {
        av[t] = a_src[16 * t + nl];
        dv[t] = a_dst[16 * t + nl];
    }
#pragma unroll
    for (int reg = 0; reg < 4; reg++) {
        float t0 = acc[0][reg] * av[0] + acc[1][reg] * av[1];
        float t1 = acc[2][reg] * av[2] + acc[3][reg] * av[3];
        float t2 = acc[4][reg] * av[4] + acc[5][reg] * av[5];
        float t3 = acc[6][reg] * av[6] + acc[7][reg] * av[7];
        float d0 = acc[0][reg] * dv[0] + acc[1][reg] * dv[1];
        float d1 = acc[2][reg] * dv[2] + acc[3][reg] * dv[3];
        float d2 = acc[4][reg] * dv[4] + acc[5][reg] * dv[5];
        float d3 = acc[6][reg] * dv[6] + acc[7][reg] * dv[7];
#pragma unroll
        for (int off = 1; off <= 8; off <<= 1) {
            t0 += __shfl_xor(t0, off); t1 += __shfl_xor(t1, off);
            t2 += __shfl_xor(t2, off); t3 += __shfl_xor(t3, off);
            d0 += __shfl_xor(d0, off); d1 += __shfl_xor(d1, off);
            d2 += __shfl_xor(d2, off); d3 += __shfl_xor(d3, off);
        }
        int row = row_blk + wrow + q * 4 + reg;
        if (row < n && nl < 4) {
            float ts = nl == 0 ? t0 : nl == 1 ? t1 : nl == 2 ? t2 : t3;
            float td = nl == 0 ? d0 : nl == 1 ? d1 : nl == 2 ? d2 : d3;
            s_src[row * 4 + nl] = ts;
            s_dst[row * 4 + nl] = td;
        }
    }

    // h8: transpose acc through LDS (bf16) then pack fp8 coalesced
#pragma unroll
    for (int t = 0; t < 8; t++) {
#pragma unroll
        for (int reg = 0; reg < 4; reg++) {
            __hip_bfloat16 b = __float2bfloat16(acc[t][reg]);
            hs[(wrow + q * 4 + reg) * 128 + 16 * t + nl] = *(unsigned short*)&b;
        }
    }
    __syncthreads();
    const unsigned* hsu = (const unsigned*)hs;
#pragma unroll
    for (int i = 0; i < 16; i++) {
        int pidx = tid + i * 256;             // channel-pair index in 64x64
        int rl = pidx >> 6, cp = pidx & 63;
        int row = row_blk + rl;
        if (row < n) {
            unsigned u = hsu[rl * 64 + cp];
            float f0 = __uint_as_float(u << 16);
            float f1 = __uint_as_float(u & 0xFFFF0000u);
            h8[(size_t)row * 64 + cp] = pack_fp8x2(f0, f1);
        }
    }
}

// ---------------------------------------------------------------------------
// Softmax-aggregation: chunked score phase + shuffle-broadcast inner loop.
// VAL_RES: residual reconstructed from val0 (layer 1) instead of reading the
// 25.6 MB x_prev buffer.  OUT_BF16: emit bf16 rows (consumed only by MFMA mlp,
// which packs to bf16 anyway -> identical bits, half the write+read traffic).
template <bool VAL_RES, bool OUT_BF16>
__global__ __launch_bounds__(256) void agg_kernel(
    const unsigned char* __restrict__ h8,   // fp8 e4m3, [n][128]
    const float* __restrict__ s_src, const float* __restrict__ s_dst,
    const int* __restrict__ row_ptr, const unsigned* __restrict__ col,
    const float* __restrict__ tab, const float* __restrict__ bias,
    const float* __restrict__ x_prev,
    const float* __restrict__ val0, const float* __restrict__ W0s,
    const float* __restrict__ bias0,
    void* __restrict__ x_out, int n) {
    __shared__ __align__(16) float stab_s[68];
    if (threadIdx.x < 68) stab_s[threadIdx.x] = tab[threadIdx.x];
    __syncthreads();

    int d = __builtin_amdgcn_readfirstlane(blockIdx.x * 4 + (threadIdx.x >> 6));
    if (d >= n) return;
    int lane = threadIdx.x & 63;
    int strm = lane >> 4;             // 0..3
    int l16 = lane & 15;              // channel group within row
    int head = l16 >> 2;              // 4 lanes/head

    int start = row_ptr[d], end = row_ptr[d + 1];
    float4 sd4 = ((const float4*)s_dst)[d];

    float den = 0.f;
    float a0 = 0.f, a1 = 0.f, a2 = 0.f, a3 = 0.f;
    float a4 = 0.f, a5 = 0.f, a6 = 0.f, a7 = 0.f;

    if (strm == 0) {                  // self edge (typ=16, mean attr)
        float sdh = head == 0 ? sd4.x : head == 1 ? sd4.y : head == 2 ? sd4.z : sd4.w;
        float s = s_src[d * 4 + head] + sdh + stab_s[64 + head];
        s = s > 0.f ? s : 0.2f * s;
        float w = __expf(s);
        uint2 u = ((const uint2*)(h8 + (size_t)d * 128))[l16];
        floatx2 f01 = __builtin_amdgcn_cvt_pk_f32_fp8((int)u.x, false);
        floatx2 f23 = __builtin_amdgcn_cvt_pk_f32_fp8((int)u.x, true);
        floatx2 f45 = __builtin_amdgcn_cvt_pk_f32_fp8((int)u.y, false);
        floatx2 f67 = __builtin_amdgcn_cvt_pk_f32_fp8((int)u.y, true);
        den = w;
        a0 = w * f01.x;  a1 = w * f01.y;
        a2 = w * f23.x;  a3 = w * f23.y;
        a4 = w * f45.x;  a5 = w * f45.y;
        a6 = w * f67.x;  a7 = w * f67.y;
    }

    for (int base = start; base < end; base += 64) {
        // score phase: lane computes edge base+lane's 4 head-weights
        float4 w4 = make_float4(0.f, 0.f, 0.f, 0.f);
        int esrc = 0;
        int e = base + lane;
        if (e < end) {
            unsigned pp = col[e];
            esrc = (int)(pp & 0xFFFFu);
            int typ = (int)(pp >> 16);
            float4 ss4 = ((const float4*)s_src)[esrc];
            float4 st4 = *(const float4*)&stab_s[typ * 4];
            float s0 = ss4.x + sd4.x + st4.x;
            float s1 = ss4.y + sd4.y + st4.y;
            float s2 = ss4.z + sd4.z + st4.z;
            float s3 = ss4.w + sd4.w + st4.w;
            s0 = s0 > 0.f ? s0 : 0.2f * s0;
            s1 = s1 > 0.f ? s1 : 0.2f * s1;
            s2 = s2 > 0.f ? s2 : 0.2f * s2;
            s3 = s3 > 0.f ? s3 : 0.2f * s3;
            w4.x = __expf(s0); w4.y = __expf(s1);
            w4.z = __expf(s2); w4.w = __expf(s3);
        }
        int C = min(64, end - base);
        int steps = (C + 3) >> 2;
        for (int i = 0; i < steps; i++) {
            int j = i * 4 + strm;             // padding lanes carry w4 = 0
            float wx = __shfl(w4.x, j);
            float wy = __shfl(w4.y, j);
            float wz = __shfl(w4.z, j);
            float ww = __shfl(w4.w, j);
            int sj = __shfl(esrc, j);
            float w = head == 0 ? wx : head == 1 ? wy : head == 2 ? wz : ww;
            uint2 u = ((const uint2*)(h8 + (size_t)sj * 128))[l16];
            floatx2 f01 = __builtin_amdgcn_cvt_pk_f32_fp8((int)u.x, false);
            floatx2 f23 = __builtin_amdgcn_cvt_pk_f32_fp8((int)u.x, true);
            floatx2 f45 = __builtin_amdgcn_cvt_pk_f32_fp8((int)u.y, false);
            floatx2 f67 = __builtin_amdgcn_cvt_pk_f32_fp8((int)u.y, true);
            den += w;
            a0 = fmaf(w, f01.x, a0);  a1 = fmaf(w, f01.y, a1);
            a2 = fmaf(w, f23.x, a2);  a3 = fmaf(w, f23.y, a3);
            a4 = fmaf(w, f45.x, a4);  a5 = fmaf(w, f45.y, a5);
            a6 = fmaf(w, f67.x, a6);  a7 = fmaf(w, f67.y, a7);
        }
    }

    // merge 4 streams: plain sums, xor16 then xor32
#pragma unroll
    for (int off = 16; off <= 32; off <<= 1) {
        den += __shfl_xor(den, off);
        a0 += __shfl_xor(a0, off);  a1 += __shfl_xor(a1, off);
        a2 += __shfl_xor(a2, off);  a3 += __shfl_xor(a3, off);
        a4 += __shfl_xor(a4, off);  a5 += __shfl_xor(a5, off);
        a6 += __shfl_xor(a6, off);  a7 += __shfl_xor(a7, off);
    }

    if (lane < 16) {
        float inv = 1.f / (den + 1e-16f);
        float4 b0 = ((const float4*)bias)[2 * l16];
        float4 b1v = ((const float4*)bias)[2 * l16 + 1];
        float4 o0v, o1v;
        o0v.x = a0 * inv + b0.x;  o0v.y = a1 * inv + b0.y;
        o0v.z = a2 * inv + b0.z;  o0v.w = a3 * inv + b0.w;
        o1v.x = a4 * inv + b1v.x; o1v.y = a5 * inv + b1v.y;
        o1v.z = a6 * inv + b1v.z; o1v.w = a7 * inv + b1v.w;
        if (VAL_RES) {
            // residual = relu(val0[d][head]*W0s[c]+bias0[c]) (bit-identical to xa)
            float vv = val0[d * 4 + head];
            float4 wa = ((const float4*)W0s)[2 * l16];
            float4 wb = ((const float4*)W0s)[2 * l16 + 1];
            float4 ba = ((const float4*)bias0)[2 * l16];
            float4 bb = ((const float4*)bias0)[2 * l16 + 1];
            o0v.x += fmaxf(fmaf(vv, wa.x, ba.x), 0.f);
            o0v.y += fmaxf(fmaf(vv, wa.y, ba.y), 0.f);
            o0v.z += fmaxf(fmaf(vv, wa.z, ba.z), 0.f);
            o0v.w += fmaxf(fmaf(vv, wa.w, ba.w), 0.f);
            o1v.x += fmaxf(fmaf(vv, wb.x, bb.x), 0.f);
            o1v.y += fmaxf(fmaf(vv, wb.y, bb.y), 0.f);
            o1v.z += fmaxf(fmaf(vv, wb.z, bb.z), 0.f);
            o1v.w += fmaxf(fmaf(vv, wb.w, bb.w), 0.f);
        } else if (x_prev) {
            float4 p0 = ((const float4*)x_prev)[(size_t)d * 32 + 2 * l16];
            float4 p1 = ((const float4*)x_prev)[(size_t)d * 32 + 2 * l16 + 1];
            o0v.x += p0.x; o0v.y += p0.y; o0v.z += p0.z; o0v.w += p0.w;
            o1v.x += p1.x; o1v.y += p1.y; o1v.z += p1.z; o1v.w += p1.w;
        }
        o0v.x = fmaxf(o0v.x, 0.f); o0v.y = fmaxf(o0v.y, 0.f);
        o0v.z = fmaxf(o0v.z, 0.f); o0v.w = fmaxf(o0v.w, 0.f);
        o1v.x = fmaxf(o1v.x, 0.f); o1v.y = fmaxf(o1v.y, 0.f);
        o1v.z = fmaxf(o1v.z, 0.f); o1v.w = fmaxf(o1v.w, 0.f);
        if (OUT_BF16) {
            uint4 pk;
            pk.x = pack_bf2(o0v.x, o0v.y);
            pk.y = pack_bf2(o0v.z, o0v.w);
            pk.z = pack_bf2(o1v.x, o1v.y);
            pk.w = pack_bf2(o1v.z, o1v.w);
            ((uint4*)x_out)[(size_t)d * 16 + l16] = pk;
        } else {
            ((float4*)x_out)[(size_t)d * 32 + 2 * l16]     = o0v;
            ((float4*)x_out)[(size_t)d * 32 + 2 * l16 + 1] = o1v;
        }
    }
}

// ---------------------------------------------------------------------------
// MLP head via MFMA, bf16 input rows: 7 col-tiles (hidden >=100 zero-padded).
__global__ __launch_bounds__(256, 2) void mlp_kernel(
    const unsigned short* __restrict__ Xbf, const unsigned* __restrict__ W1q,
    const float* __restrict__ b1, const float* __restrict__ W2,
    const float* __restrict__ b2, float* __restrict__ out, int n) {
    int tid = threadIdx.x;
    int lane = tid & 63;
    int wv = tid >> 6;
    int q = lane >> 4, nl = lane & 15;
    int row_blk = blockIdx.x * 64;
    int wrow = wv * 16;

    int arow = row_blk + wrow + nl;
    if (arow >= n) arow = n - 1;
    const uint4* Xr = (const uint4*)(Xbf + (size_t)arow * HCONC);

    f32x4 acc[7];
#pragma unroll
    for (int t = 0; t < 7; t++) acc[t] = (f32x4){0.f, 0.f, 0.f, 0.f};

    const uint4* Wp4 = (const uint4*)W1q;
#pragma unroll
    for (int kb = 0; kb < 4; kb++) {
        uint4 ua = Xr[kb * 4 + q];            // channels 32kb+8q .. +7 (bf16)
        bf16x8 af = __builtin_bit_cast(bf16x8, ua);
#pragma unroll
        for (int t = 0; t < 7; t++) {
            uint4 ub = Wp4[(t * 4 + kb) * 64 + lane];
            bf16x8 bf = __builtin_bit_cast(bf16x8, ub);
            acc[t] = __builtin_amdgcn_mfma_f32_16x16x32_bf16(af, bf, acc[t], 0, 0, 0);
        }
    }

    float b1c[7], w2c[7];
#pragma unroll
    for (int t = 0; t < 7; t++) {
        int c = 16 * t + nl;
        bool vld = c < 100;
        b1c[t] = vld ? b1[c] : 0.f;
        w2c[t] = vld ? W2[c] : 0.f;
    }
    float b2v = b2[0];

#pragma unroll
    for (int reg = 0; reg < 4; reg++) {
        float sum = 0.f;
#pragma unroll
        for (int t = 0; t < 7; t++) {
            float hv = fmaxf(acc[t][reg] + b1c[t], 0.f);
            sum = fmaf(hv, w2c[t], sum);
        }
#pragma unroll
        for (int off = 1; off <= 8; off <<= 1)
            sum += __shfl_xor(sum, off);
        int row = row_blk + wrow + q * 4 + reg;
        if (nl == 0 && row < n)
            out[row] = 1.f / (1.f + __expf(-(sum + b2v)));
    }
}

// ---------------------------------------------------------------------------
extern "C" void kernel_launch(void* const* d_in, const int* in_sizes, int n_in,
                              void* d_out, int out_size, void* d_ws, size_t ws_size,
                              hipStream_t stream) {
    const float* x       = (const float*)d_in[0];
    const int*   ei      = (const int*)d_in[1];     // [2,E]: src then dst
    const int*   etype   = (const int*)d_in[2];
    const float* emb     = (const float*)d_in[3];   // [16,8]
    const float* W_l0    = (const float*)d_in[4];   // [32,128]
    const float* W_l1    = (const float*)d_in[5];   // [128,128]
    const float* W_l2    = (const float*)d_in[6];   // [128,128]
    const float* att_src = (const float*)d_in[7];   // [3,4,32]
    const float* att_dst = (const float*)d_in[8];
    const float* att_edge= (const float*)d_in[9];
    const float* W_edge  = (const float*)d_in[10];  // [3,8,128]
    const float* bias    = (const float*)d_in[11];  // [3,128]
    const float* mW1     = (const float*)d_in[12];  // [128,100]
    const float* mb1     = (const float*)d_in[13];
    const float* mW2     = (const float*)d_in[14];  // [100,1]
    const float* mb2     = (const float*)d_in[15];

    int n = in_sizes[0];   // 50000
    int E = in_sizes[2];   // 800000
    int nbuk = (n + 255) >> 8;   // 196
    int nA = (E + TILE - 1) / TILE;   // 391

    // workspace carve (keep 16-byte alignment for uint4 views)
    float* p   = (float*)d_ws;
    float* xa  = p; p += (size_t)n * HCONC;        // agg2 bf16 out lives here too
    float* xb  = p; p += (size_t)n * HCONC;
    float* ssrc = p; p += (size_t)n * NHEAD;
    float* sdst = p; p += (size_t)n * NHEAD;
    float* val0 = p; p += (size_t)n * NHEAD;       // layer-0 rank-1 output
    float* hbf  = p; p += (size_t)n * 32;          // fp8 h buffer (n*128 bytes)
    unsigned* Wl1q = (unsigned*)p; p += 8192;      // MFMA-B-packed W_l1
    unsigned* Wl2q = (unsigned*)p; p += 8192;      // MFMA-B-packed W_l2
    unsigned* W1q  = (unsigned*)p; p += 7168;      // MFMA-B-packed mW1 (7 tiles)
    int* row_ptr     = (int*)p;
    int* gcursor     = row_ptr + n + 1;
    int* cnt         = gcursor + 256;
    float* W0s    = (float*)(cnt + 16);
    float* SA0    = W0s + HCONC;
    float* SD0    = SA0 + NHEAD;
    float* meanat = SD0 + NHEAD;     // unused (kept for layout stability)
    float* stab   = meanat + EDIM;   // 3*68 = 204, round to 256
    char* raw = (char*)(stab + 256);
    unsigned* ebuf = (unsigned*)(((uintptr_t)raw + 15) & ~(uintptr_t)15); // nbuk*BCAP u32
    unsigned* col = ebuf + (size_t)nbuk * BCAP;                          // E entries

    // CSR build: memset cursors -> binA (binning + weight pack + setup riding
    // along) -> binB (fine sort + fused layer-0 -> val0 only)
    hipMemsetAsync(gcursor, 0, (256 + 16) * sizeof(int), stream);
    binA_kernel<<<nA + 93, 256, 0, stream>>>(ei, etype, E, nbuk, nA, gcursor, cnt,
                                             ebuf, W_l1, W_l2, mW1, Wl1q, Wl2q, W1q,
                                             W_l0, emb, att_src, att_dst, att_edge,
                                             W_edge, W0s, SA0, SD0, stab);
    binB_kernel<<<nbuk, 256, 0, stream>>>(ebuf, gcursor, n, nbuk, row_ptr, col,
                                          cnt, stab, E, x, SA0, SD0, val0);

    // layer 1: transform reconstructs rows from val0 (no xa materialization)
    transform0_kernel<<<(n + 63) / 64, 256, 0, stream>>>(val0, W0s, bias + 0, Wl1q,
                                                         att_src + 128, att_dst + 128,
                                                         (unsigned short*)hbf, ssrc, sdst, n);
    agg_kernel<true, false><<<(n + 3) / 4, 256, 0, stream>>>(
        (const unsigned char*)hbf, ssrc, sdst, row_ptr, col,
        stab + 68, bias + 128, nullptr, val0, W0s, bias + 0, xb, n);
    // layer 2
    transform_kernel<<<(n + 63) / 64, 256, 0, stream>>>(xb, Wl2q, att_src + 256, att_dst + 256,
                                                        (unsigned short*)hbf, ssrc, sdst, n);
    agg_kernel<false, true><<<(n + 3) / 4, 256, 0, stream>>>(
        (const unsigned char*)hbf, ssrc, sdst, row_ptr, col,
        stab + 136, bias + 256, xb, nullptr, nullptr, nullptr, xa, n);
    // MLP head (MFMA, bf16 input)
    mlp_kernel<<<(n + 63) / 64, 256, 0, stream>>>((const unsigned short*)xa, W1q,
                                                  mb1, mW2, mb2, (float*)d_out, n);
}

// Round 3
// 242.299 us; speedup vs baseline: 1.0802x; 1.0188x over previous
//
#include <hip/hip_runtime.h>
#include <hip/hip_bf16.h>
#include <hip/hip_fp16.h>

#define HCONC 128   // H*C
#define NHEAD 4
#define CCH   32
#define EDIM  8
#define NREL  16
#define BCAP  5120  // per-bucket capacity (mean ~4081, +16 sigma headroom)
#define TILE  2048  // edges per binA block

typedef float floatx2 __attribute__((ext_vector_type(2)));
typedef short bf16x8 __attribute__((ext_vector_type(8)));
typedef float f32x4 __attribute__((ext_vector_type(4)));

__device__ inline unsigned short pack_fp8x2(float a, float b) {
    return (unsigned short)(__builtin_amdgcn_cvt_pk_fp8_f32(a, b, 0, false) & 0xFFFF);
}
__device__ inline unsigned pack_bf2(float lo, float hi) {
    __hip_bfloat162 v;
    v.x = __float2bfloat16(lo);
    v.y = __float2bfloat16(hi);
    return *(unsigned*)&v;
}

// ---------------------------------------------------------------------------
// binA: tile-local counting sort by dst-bucket, coalesced run writes.
// Blocks [nA, nA+92): MFMA weight packing.  Block nA+92: setup.
// Cursors are RELATIVE (zero-initialized by a tiny memset before launch).
// ebuf record: src(16) | typ(4)<<16 | (dst&255)<<20  -- bucket implicit.
__global__ __launch_bounds__(256) void binA_kernel(
    const int* __restrict__ ei, const int* __restrict__ etype, int E, int nbuk, int nA,
    int* __restrict__ gcursor, int* __restrict__ cnt, unsigned* __restrict__ ebuf,
    const float* __restrict__ W_l1, const float* __restrict__ W_l2,
    const float* __restrict__ mW1,
    unsigned* __restrict__ Wl1q, unsigned* __restrict__ Wl2q, unsigned* __restrict__ W1q,
    const float* __restrict__ W_l0, const float* __restrict__ emb,
    const float* __restrict__ att_src, const float* __restrict__ att_dst,
    const float* __restrict__ att_edge, const float* __restrict__ W_edge,
    float* __restrict__ W0s, float* __restrict__ SA0, float* __restrict__ SD0,
    float* __restrict__ stab) {
    __shared__ int hist[256], lbase[256], gbase[256], tmp[256];
    __shared__ int lcnt16[NREL];
    __shared__ unsigned srt[TILE];
    __shared__ unsigned char sbuk[TILE];
    __shared__ float W0s_s[HCONC];
    int t = threadIdx.x;

    if ((int)blockIdx.x >= nA) {               // ---- pack / setup blocks ----
        int pb = (int)blockIdx.x - nA;
        if (pb == 92) {                        // setup (weights only; no cnt dep)
            if (t < HCONC) {
                float s = 0.f;
                for (int k = 0; k < CCH; k++) s += W_l0[k * HCONC + t];
                W0s[t] = s; W0s_s[t] = s;
            }
            __syncthreads();
            if (t < NHEAD) {
                float sa = 0.f, sd = 0.f;
                for (int c = 0; c < CCH; c++) {
                    sa += W0s_s[t * CCH + c] * att_src[t * CCH + c];
                    sd += W0s_s[t * CCH + c] * att_dst[t * CCH + c];
                }
                SA0[t] = sa; SD0[t] = sd;
            }
            if (t < 192) {                     // 3 layers x 16 types x 4 heads
                int l = t >> 6, rem = t & 63, typ = rem >> 2, hh = rem & 3;
                const float* attr = emb + typ * EDIM;
                const float* We = W_edge + l * EDIM * HCONC;
                const float* ae = att_edge + l * HCONC + hh * CCH;
                float s = 0.f;
                for (int c = 0; c < CCH; c++) {
                    float ev = 0.f;
                    for (int dd = 0; dd < EDIM; dd++)
                        ev += attr[dd] * We[dd * HCONC + hh * CCH + c];
                    s += ev * ae[c];
                }
                stab[l * 68 + typ * 4 + hh] = s;   // mean entries filled by binB b==0
            }
            return;
        }
        int i = pb * 256 + t;
        if (i < 16384) {                       // MFMA B-pack (W_l1 then W_l2)
            const float* W = (i < 8192) ? W_l1 : W_l2;
            unsigned* dst = (i < 8192) ? Wl1q : Wl2q;
            int r = i & 8191;
            int j2 = r & 3, lane = (r >> 2) & 63, kb = (r >> 8) & 3, tt = r >> 10;
            int k0 = kb * 32 + ((lane >> 4) & 3) * 8 + 2 * j2;
            int c = 16 * tt + (lane & 15);
            dst[r] = pack_bf2(W[k0 * 128 + c], W[(k0 + 1) * 128 + c]);
        } else if (i < 16384 + 7168) {         // mlp W1 B-pack, 7 tiles
            int r = i - 16384;
            int j2 = r & 3, lane = (r >> 2) & 63, kb = (r >> 8) & 3, tt = r >> 10;
            int k0 = kb * 32 + ((lane >> 4) & 3) * 8 + 2 * j2;
            int c = 16 * tt + (lane & 15);
            float lo = (c < 100) ? mW1[k0 * 100 + c] : 0.f;
            float hi = (c < 100) ? mW1[(k0 + 1) * 100 + c] : 0.f;
            W1q[r] = pack_bf2(lo, hi);
        }
        return;
    }

    // ---- edge binning ----
    hist[t] = 0;
    if (t < NREL) lcnt16[t] = 0;
    __syncthreads();

    int base = blockIdx.x * TILE;
    int count = min(TILE, E - base);

    unsigned rec[8]; int slot[8]; int buk[8];
#pragma unroll
    for (int i = 0; i < 8; i++) {
        int idx = t + i * 256;
        if (idx < count) {
            int g = base + idx;
            int s = ei[g], d = ei[E + g], ty = etype[g];
            rec[i] = (unsigned)s | ((unsigned)ty << 16) | ((unsigned)(d & 255) << 20);
            buk[i] = d >> 8;
            slot[i] = atomicAdd(&hist[buk[i]], 1);
            atomicAdd(&lcnt16[ty], 1);
        } else buk[i] = -1;
    }
    __syncthreads();

    int v = hist[t];
    tmp[t] = v; __syncthreads();
    for (int off = 1; off < 256; off <<= 1) {
        int add = (t >= off) ? tmp[t - off] : 0; __syncthreads();
        tmp[t] += add; __syncthreads();
    }
    lbase[t] = tmp[t] - v;
    if (t < nbuk && v > 0) gbase[t] = atomicAdd(&gcursor[t], v);  // relative reserve
    __syncthreads();

#pragma unroll
    for (int i = 0; i < 8; i++)
        if (buk[i] >= 0) {
            int pos = lbase[buk[i]] + slot[i];
            srt[pos] = rec[i];
            sbuk[pos] = (unsigned char)buk[i];
        }
    if (t < NREL) atomicAdd(&cnt[t], lcnt16[t]);
    __syncthreads();

    for (int idx = t; idx < count; idx += 256) {
        unsigned r = srt[idx];
        int bk = sbuk[idx];
        int rel = gbase[bk] + idx - lbase[bk];
        if (rel < BCAP) ebuf[bk * BCAP + rel] = r;   // cap guard (never trips)
    }
}

// ---------------------------------------------------------------------------
// binB: per-bucket fine sort + FUSED layer-0 aggregation -> val0[n][4] only
// (rank-1 layer-0 output; consumers reconstruct rows on the fly).
__global__ __launch_bounds__(256) void binB_kernel(
    const unsigned* __restrict__ ebuf, const int* __restrict__ gcursor,
    int n, int nbuk,
    int* __restrict__ row_ptr, unsigned* __restrict__ col,
    const int* __restrict__ cnt, float* __restrict__ stab, int E,
    const float* __restrict__ x,
    const float* __restrict__ SA0, const float* __restrict__ SD0,
    float* __restrict__ val0) {
    __shared__ int hist[256], lcur[256], tmp[256];
    __shared__ unsigned colsl[BCAP];            // 20 KB
    __shared__ __align__(16) float stab0[68];
    int b = blockIdx.x, t = threadIdx.x;

    if (t < 64) stab0[t] = stab[t];             // layer-0 per-type entries
    float invE = 1.f / (float)E;
    if (t < 4) {                                // local layer-0 mean entry
        float s = 0.f;
        for (int r = 0; r < NREL; r++) s += (float)cnt[r] * stab[r * 4 + t];
        stab0[64 + t] = s * invE;
    }

    // inline bucket-base scan (gcursor holds per-bucket sizes)
    int c = (t < nbuk) ? gcursor[t] : 0;
    tmp[t] = c; __syncthreads();
    for (int off = 1; off < 256; off <<= 1) {
        int add = (t >= off) ? tmp[t - off] : 0; __syncthreads();
        tmp[t] += add; __syncthreads();
    }
    int gstart = (b == 0) ? 0 : tmp[b - 1];
    if (b == 0 && t == nbuk - 1) row_ptr[n] = tmp[t];   // total edge count
    if (b == 0 && t < 12) {                     // global mean entries, layers 0-2
        int l = t >> 2, hh = t & 3;
        float s = 0.f;
        for (int r = 0; r < NREL; r++) s += (float)cnt[r] * stab[l * 68 + r * 4 + hh];
        stab[l * 68 + 64 + hh] = s * invE;
    }
    __syncthreads();

    int bbase = b * BCAP;
    int cntb = min(gcursor[b], BCAP);
    hist[t] = 0;
    __syncthreads();
    for (int i = t; i < cntb; i += 256) {
        unsigned r = ebuf[bbase + i];
        atomicAdd(&hist[r >> 20], 1);
    }
    __syncthreads();
    int v = hist[t];
    tmp[t] = v; __syncthreads();
    for (int off = 1; off < 256; off <<= 1) {
        int add = (t >= off) ? tmp[t - off] : 0; __syncthreads();
        tmp[t] += add; __syncthreads();
    }
    lcur[t] = tmp[t] - v;
    int gdst = (b << 8) + t;
    if (gdst < n) row_ptr[gdst] = gstart + tmp[t] - v;
    __syncthreads();
    for (int i = t; i < cntb; i += 256) {
        unsigned r = ebuf[bbase + i];
        int pos = atomicAdd(&lcur[r >> 20], 1);
        colsl[pos] = r & 0xFFFFFu;              // src | typ<<16
    }
    __syncthreads();
    for (int i = t; i < cntb; i += 256)
        col[gstart + i] = colsl[i];

    // ---- fused layer-0 aggregation (h0 is rank-1: per-(dst,head) scalar) ----
    int lo = tmp[t] - v, hi = tmp[t];           // this dst's range in colsl
    if (gdst < n) {
        float xd = x[gdst];
        float4 sa4 = *(const float4*)SA0;
        float4 sdc = *(const float4*)SD0;
        float sd0 = xd * sdc.x, sd1 = xd * sdc.y, sd2 = xd * sdc.z, sd3 = xd * sdc.w;
        // self edge (typ=16 -> mean attr)
        float s0 = fmaf(xd, sa4.x, sd0) + stab0[64];
        float s1 = fmaf(xd, sa4.y, sd1) + stab0[65];
        float s2 = fmaf(xd, sa4.z, sd2) + stab0[66];
        float s3 = fmaf(xd, sa4.w, sd3) + stab0[67];
        s0 = s0 > 0.f ? s0 : 0.2f * s0;
        s1 = s1 > 0.f ? s1 : 0.2f * s1;
        s2 = s2 > 0.f ? s2 : 0.2f * s2;
        s3 = s3 > 0.f ? s3 : 0.2f * s3;
        float w0 = __expf(s0), w1 = __expf(s1), w2 = __expf(s2), w3 = __expf(s3);
        float den0 = w0, den1 = w1, den2 = w2, den3 = w3;
        float sx0 = w0 * xd, sx1 = w1 * xd, sx2 = w2 * xd, sx3 = w3 * xd;
        for (int j = lo; j < hi; j++) {
            unsigned p = colsl[j];
            float xv = x[p & 0xFFFFu];
            int typ = (int)(p >> 16);
            float4 st = *(const float4*)&stab0[typ * 4];
            float e0 = fmaf(xv, sa4.x, sd0) + st.x;
            float e1 = fmaf(xv, sa4.y, sd1) + st.y;
            float e2 = fmaf(xv, sa4.z, sd2) + st.z;
            float e3 = fmaf(xv, sa4.w, sd3) + st.w;
            e0 = e0 > 0.f ? e0 : 0.2f * e0;
            e1 = e1 > 0.f ? e1 : 0.2f * e1;
            e2 = e2 > 0.f ? e2 : 0.2f * e2;
            e3 = e3 > 0.f ? e3 : 0.2f * e3;
            float g0 = __expf(e0), g1 = __expf(e1), g2 = __expf(e2), g3 = __expf(e3);
            den0 += g0; den1 += g1; den2 += g2; den3 += g3;
            sx0 = fmaf(g0, xv, sx0); sx1 = fmaf(g1, xv, sx1);
            sx2 = fmaf(g2, xv, sx2); sx3 = fmaf(g3, xv, sx3);
        }
        float4 vo;
        vo.x = sx0 / (den0 + 1e-16f);
        vo.y = sx1 / (den1 + 1e-16f);
        vo.z = sx2 / (den2 + 1e-16f);
        vo.w = sx3 / (den3 + 1e-16f);
        ((float4*)val0)[gdst] = vo;
    }
}

// ---------------------------------------------------------------------------
// Layer-1 transform: A rows reconstructed in-register from val0 (rank-1 layer-0
// output), B = MFMA-packed W_l1.  Bit-identical to reading the materialized xa.
__global__ __launch_bounds__(256, 2) void transform0_kernel(
    const float* __restrict__ val0, const float* __restrict__ W0s,
    const float* __restrict__ bias0, const unsigned* __restrict__ Wq,
    const float* __restrict__ a_src, const float* __restrict__ a_dst,
    unsigned short* __restrict__ h8, float* __restrict__ s_src,
    float* __restrict__ s_dst, int n) {
    __shared__ unsigned short hs[64 * 128];   // 16 KB epilogue transpose
    int tid = threadIdx.x;
    int lane = tid & 63;
    int wv = tid >> 6;
    int q = lane >> 4, nl = lane & 15;
    int row_blk = blockIdx.x * 64;
    int wrow = wv * 16;

    int arow = row_blk + wrow + nl;
    if (arow >= n) arow = n - 1;              // clamp; stores are guarded
    float4 v4 = ((const float4*)val0)[arow];

    f32x4 acc[8];
#pragma unroll
    for (int t = 0; t < 8; t++) acc[t] = (f32x4){0.f, 0.f, 0.f, 0.f};

    const uint4* Wp4 = (const uint4*)Wq;
#pragma unroll
    for (int kb = 0; kb < 4; kb++) {
        int c4 = 8 * kb + 2 * q;              // float4 index of channel block
        float4 wa = ((const float4*)W0s)[c4];
        float4 wb = ((const float4*)W0s)[c4 + 1];
        float4 ba = ((const float4*)bias0)[c4];
        float4 bb = ((const float4*)bias0)[c4 + 1];
        float vr = kb == 0 ? v4.x : kb == 1 ? v4.y : kb == 2 ? v4.z : v4.w;
        float x0 = fmaxf(fmaf(vr, wa.x, ba.x), 0.f);
        float x1 = fmaxf(fmaf(vr, wa.y, ba.y), 0.f);
        float x2 = fmaxf(fmaf(vr, wa.z, ba.z), 0.f);
        float x3 = fmaxf(fmaf(vr, wa.w, ba.w), 0.f);
        float x4 = fmaxf(fmaf(vr, wb.x, bb.x), 0.f);
        float x5 = fmaxf(fmaf(vr, wb.y, bb.y), 0.f);
        float x6 = fmaxf(fmaf(vr, wb.z, bb.z), 0.f);
        float x7 = fmaxf(fmaf(vr, wb.w, bb.w), 0.f);
        uint4 ua;
        ua.x = pack_bf2(x0, x1);
        ua.y = pack_bf2(x2, x3);
        ua.z = pack_bf2(x4, x5);
        ua.w = pack_bf2(x6, x7);
        bf16x8 af = __builtin_bit_cast(bf16x8, ua);
#pragma unroll
        for (int t = 0; t < 8; t++) {
            uint4 ub = Wp4[(t * 4 + kb) * 64 + lane];
            bf16x8 bf = __builtin_bit_cast(bf16x8, ub);
            acc[t] = __builtin_amdgcn_mfma_f32_16x16x32_bf16(af, bf, acc[t], 0, 0, 0);
        }
    }

    // scores: lane holds col c=16t+nl of rows wrow+q*4+reg
    float av[8], dv[8];
#pragma unroll
    for (int t = 0; t < 8; t++) {
        av[t] = a_src[16 * t + nl];
        dv[t] = a_dst[16 * t + nl];
    }
#pragma unroll
    for (int reg = 0; reg < 4; reg++) {
        float t0 = acc[0][reg] * av[0] + acc[1][reg] * av[1];
        float t1 = acc[2][reg] * av[2] + acc[3][reg] * av[3];
        float t2 = acc[4][reg] * av[4] + acc[5][reg] * av[5];
        float t3 = acc[6][reg] * av[6] + acc[7][reg] * av[7];
        float d0 = acc[0][reg] * dv[0] + acc[1][reg] * dv[1];
        float d1 = acc[2][reg] * dv[2] + acc[3][reg] * dv[3];
        float d2 = acc[4][reg] * dv[4] + acc[5][reg] * dv[5];
        float d3 = acc[6][reg] * dv[6] + acc[7][reg] * dv[7];
#pragma unroll
        for (int off = 1; off <= 8; off <<= 1) {
            t0 += __shfl_xor(t0, off); t1 += __shfl_xor(t1, off);
            t2 += __shfl_xor(t2, off); t3 += __shfl_xor(t3, off);
            d0 += __shfl_xor(d0, off); d1 += __shfl_xor(d1, off);
            d2 += __shfl_xor(d2, off); d3 += __shfl_xor(d3, off);
        }
        int row = row_blk + wrow + q * 4 + reg;
        if (row < n && nl < 4) {
            float ts = nl == 0 ? t0 : nl == 1 ? t1 : nl == 2 ? t2 : t3;
            float td = nl == 0 ? d0 : nl == 1 ? d1 : nl == 2 ? d2 : d3;
            s_src[row * 4 + nl] = ts;
            s_dst[row * 4 + nl] = td;
        }
    }

    // h8: transpose acc through LDS (bf16) then pack fp8 coalesced
#pragma unroll
    for (int t = 0; t < 8; t++) {
#pragma unroll
        for (int reg = 0; reg < 4; reg++) {
            __hip_bfloat16 b = __float2bfloat16(acc[t][reg]);
            hs[(wrow + q * 4 + reg) * 128 + 16 * t + nl] = *(unsigned short*)&b;
        }
    }
    __syncthreads();
    const unsigned* hsu = (const unsigned*)hs;
#pragma unroll
    for (int i = 0; i < 16; i++) {
        int pidx = tid + i * 256;             // channel-pair index in 64x64
        int rl = pidx >> 6, cp = pidx & 63;
        int row = row_blk + rl;
        if (row < n) {
            unsigned u = hsu[rl * 64 + cp];
            float f0 = __uint_as_float(u << 16);
            float f1 = __uint_as_float(u & 0xFFFF0000u);
            h8[(size_t)row * 64 + cp] = pack_fp8x2(f0, f1);
        }
    }
}

// ---------------------------------------------------------------------------
// Dense transform via MFMA, bf16 input rows (layer 2: xb is stored bf16 —
// bit-identical to the old f32 path since MFMA consumed bf16-rounded values).
__global__ __launch_bounds__(256, 2) void transform_kernel(
    const unsigned short* __restrict__ Xbf, const unsigned* __restrict__ Wq,
    const float* __restrict__ a_src, const float* __restrict__ a_dst,
    unsigned short* __restrict__ h8, float* __restrict__ s_src,
    float* __restrict__ s_dst, int n) {
    __shared__ unsigned short hs[64 * 128];   // 16 KB epilogue transpose
    int tid = threadIdx.x;
    int lane = tid & 63;
    int wv = tid >> 6;
    int q = lane >> 4, nl = lane & 15;
    int row_blk = blockIdx.x * 64;
    int wrow = wv * 16;

    int arow = row_blk + wrow + nl;
    if (arow >= n) arow = n - 1;              // clamp; stores are guarded
    const uint4* Xr = (const uint4*)(Xbf + (size_t)arow * HCONC);

    f32x4 acc[8];
#pragma unroll
    for (int t = 0; t < 8; t++) acc[t] = (f32x4){0.f, 0.f, 0.f, 0.f};

    const uint4* Wp4 = (const uint4*)Wq;
#pragma unroll
    for (int kb = 0; kb < 4; kb++) {
        uint4 ua = Xr[kb * 4 + q];            // channels 32kb+8q .. +7 (bf16)
        bf16x8 af = __builtin_bit_cast(bf16x8, ua);
#pragma unroll
        for (int t = 0; t < 8; t++) {
            uint4 ub = Wp4[(t * 4 + kb) * 64 + lane];
            bf16x8 bf = __builtin_bit_cast(bf16x8, ub);
            acc[t] = __builtin_amdgcn_mfma_f32_16x16x32_bf16(af, bf, acc[t], 0, 0, 0);
        }
    }

    // scores: lane holds col c=16t+nl of rows wrow+q*4+reg
    float av[8], dv[8];
#pragma unroll
    for (int t = 0; t < 8; t++) {
        av[t] = a_src[16 * t + nl];
        dv[t] = a_dst[16 * t + nl];
    }
#pragma unroll
    for (int reg = 0; reg < 4; reg++) {
        float t0 = acc[0][reg] * av[0] + acc[1][reg] * av[1];
        float t1 = acc[2][reg] * av[2] + acc[3][reg] * av[3];
        float t2 = acc[4][reg] * av[4] + acc[5][reg] * av[5];
        float t3 = acc[6][reg] * av[6] + acc[7][reg] * av[7];
        float d0 = acc[0][reg] * dv[0] + acc[1][reg] * dv[1];
        float d1 = acc[2][reg] * dv[2] + acc[3][reg] * dv[3];
        float d2 = acc[4][reg] * dv[4] + acc[5][reg] * dv[5];
        float d3 = acc[6][reg] * dv[6] + acc[7][reg] * dv[7];
#pragma unroll
        for (int off = 1; off <= 8; off <<= 1) {
            t0 += __shfl_xor(t0, off); t1 += __shfl_xor(t1, off);
            t2 += __shfl_xor(t2, off); t3 += __shfl_xor(t3, off);
            d0 += __shfl_xor(d0, off); d1 += __shfl_xor(d1, off);
            d2 += __shfl_xor(d2, off); d3 += __shfl_xor(d3, off);
        }
        int row = row_blk + wrow + q * 4 + reg;
        if (row < n && nl < 4) {
            float ts = nl == 0 ? t0 : nl == 1 ? t1 : nl == 2 ? t2 : t3;
            float td = nl == 0 ? d0 : nl == 1 ? d1 : nl == 2 ? d2 : d3;
            s_src[row * 4 + nl] = ts;
            s_dst[row * 4 + nl] = td;
        }
    }

    // h8: transpose acc through LDS (bf16) then pack fp8 coalesced
#pragma unroll
    for (int t = 0; t < 8; t++) {
#pragma unroll
        for (int reg = 0; reg < 4; reg++) {
            __hip_bfloat16 b = __float2bfloat16(acc[t][reg]);
            hs[(wrow + q * 4 + reg) * 128 + 16 * t + nl] = *(unsigned short*)&b;
        }
    }
    __syncthreads();
    const unsigned* hsu = (const unsigned*)hs;
#pragma unroll
    for (int i = 0; i < 16; i++) {
        int pidx = tid + i * 256;             // channel-pair index in 64x64
        int rl = pidx >> 6, cp = pidx & 63;
        int row = row_blk + rl;
        if (row < n) {
            unsigned u = hsu[rl * 64 + cp];
            float f0 = __uint_as_float(u << 16);
            float f1 = __uint_as_float(u & 0xFFFF0000u);
            h8[(size_t)row * 64 + cp] = pack_fp8x2(f0, f1);
        }
    }
}

// ---------------------------------------------------------------------------
// Softmax-aggregation: chunked score phase + shuffle-broadcast inner loop.
// VAL_RES: residual reconstructed from val0 (layer 1).  RES_BF16: residual
// read from bf16 rows (layer 2; xb stored bf16).  OUT_BF16: emit bf16 rows.
template <bool VAL_RES, bool OUT_BF16, bool RES_BF16>
__global__ __launch_bounds__(256) void agg_kernel(
    const unsigned char* __restrict__ h8,   // fp8 e4m3, [n][128]
    const float* __restrict__ s_src, const float* __restrict__ s_dst,
    const int* __restrict__ row_ptr, const unsigned* __restrict__ col,
    const float* __restrict__ tab, const float* __restrict__ bias,
    const void* __restrict__ x_prev,
    const float* __restrict__ val0, const float* __restrict__ W0s,
    const float* __restrict__ bias0,
    void* __restrict__ x_out, int n) {
    __shared__ __align__(16) float stab_s[68];
    if (threadIdx.x < 68) stab_s[threadIdx.x] = tab[threadIdx.x];
    __syncthreads();

    int d = __builtin_amdgcn_readfirstlane(blockIdx.x * 4 + (threadIdx.x >> 6));
    if (d >= n) return;
    int lane = threadIdx.x & 63;
    int strm = lane >> 4;             // 0..3
    int l16 = lane & 15;              // channel group within row
    int head = l16 >> 2;              // 4 lanes/head

    int start = row_ptr[d], end = row_ptr[d + 1];
    float4 sd4 = ((const float4*)s_dst)[d];

    float den = 0.f;
    float a0 = 0.f, a1 = 0.f, a2 = 0.f, a3 = 0.f;
    float a4 = 0.f, a5 = 0.f, a6 = 0.f, a7 = 0.f;

    if (strm == 0) {                  // self edge (typ=16, mean attr)
        float sdh = head == 0 ? sd4.x : head == 1 ? sd4.y : head == 2 ? sd4.z : sd4.w;
        float s = s_src[d * 4 + head] + sdh + stab_s[64 + head];
        s = s > 0.f ? s : 0.2f * s;
        float w = __expf(s);
        uint2 u = ((const uint2*)(h8 + (size_t)d * 128))[l16];
        floatx2 f01 = __builtin_amdgcn_cvt_pk_f32_fp8((int)u.x, false);
        floatx2 f23 = __builtin_amdgcn_cvt_pk_f32_fp8((int)u.x, true);
        floatx2 f45 = __builtin_amdgcn_cvt_pk_f32_fp8((int)u.y, false);
        floatx2 f67 = __builtin_amdgcn_cvt_pk_f32_fp8((int)u.y, true);
        den = w;
        a0 = w * f01.x;  a1 = w * f01.y;
        a2 = w * f23.x;  a3 = w * f23.y;
        a4 = w * f45.x;  a5 = w * f45.y;
        a6 = w * f67.x;  a7 = w * f67.y;
    }

    for (int base = start; base < end; base += 64) {
        // score phase: lane computes edge base+lane's 4 head-weights
        float4 w4 = make_float4(0.f, 0.f, 0.f, 0.f);
        int esrc = 0;
        int e = base + lane;
        if (e < end) {
            unsigned pp = col[e];
            esrc = (int)(pp & 0xFFFFu);
            int typ = (int)(pp >> 16);
            float4 ss4 = ((const float4*)s_src)[esrc];
            float4 st4 = *(const float4*)&stab_s[typ * 4];
            float s0 = ss4.x + sd4.x + st4.x;
            float s1 = ss4.y + sd4.y + st4.y;
            float s2 = ss4.z + sd4.z + st4.z;
            float s3 = ss4.w + sd4.w + st4.w;
            s0 = s0 > 0.f ? s0 : 0.2f * s0;
            s1 = s1 > 0.f ? s1 : 0.2f * s1;
            s2 = s2 > 0.f ? s2 : 0.2f * s2;
            s3 = s3 > 0.f ? s3 : 0.2f * s3;
            w4.x = __expf(s0); w4.y = __expf(s1);
            w4.z = __expf(s2); w4.w = __expf(s3);
        }
        int C = min(64, end - base);
        int steps = (C + 3) >> 2;
        for (int i = 0; i < steps; i++) {
            int j = i * 4 + strm;             // padding lanes carry w4 = 0
            float wx = __shfl(w4.x, j);
            float wy = __shfl(w4.y, j);
            float wz = __shfl(w4.z, j);
            float ww = __shfl(w4.w, j);
            int sj = __shfl(esrc, j);
            float w = head == 0 ? wx : head == 1 ? wy : head == 2 ? wz : ww;
            uint2 u = ((const uint2*)(h8 + (size_t)sj * 128))[l16];
            floatx2 f01 = __builtin_amdgcn_cvt_pk_f32_fp8((int)u.x, false);
            floatx2 f23 = __builtin_amdgcn_cvt_pk_f32_fp8((int)u.x, true);
            floatx2 f45 = __builtin_amdgcn_cvt_pk_f32_fp8((int)u.y, false);
            floatx2 f67 = __builtin_amdgcn_cvt_pk_f32_fp8((int)u.y, true);
            den += w;
            a0 = fmaf(w, f01.x, a0);  a1 = fmaf(w, f01.y, a1);
            a2 = fmaf(w, f23.x, a2);  a3 = fmaf(w, f23.y, a3);
            a4 = fmaf(w, f45.x, a4);  a5 = fmaf(w, f45.y, a5);
            a6 = fmaf(w, f67.x, a6);  a7 = fmaf(w, f67.y, a7);
        }
    }

    // merge 4 streams: plain sums, xor16 then xor32
#pragma unroll
    for (int off = 16; off <= 32; off <<= 1) {
        den += __shfl_xor(den, off);
        a0 += __shfl_xor(a0, off);  a1 += __shfl_xor(a1, off);
        a2 += __shfl_xor(a2, off);  a3 += __shfl_xor(a3, off);
        a4 += __shfl_xor(a4, off);  a5 += __shfl_xor(a5, off);
        a6 += __shfl_xor(a6, off);  a7 += __shfl_xor(a7, off);
    }

    if (lane < 16) {
        float inv = 1.f / (den + 1e-16f);
        float4 b0 = ((const float4*)bias)[2 * l16];
        float4 b1v = ((const float4*)bias)[2 * l16 + 1];
        float4 o0v, o1v;
        o0v.x = a0 * inv + b0.x;  o0v.y = a1 * inv + b0.y;
        o0v.z = a2 * inv + b0.z;  o0v.w = a3 * inv + b0.w;
        o1v.x = a4 * inv + b1v.x; o1v.y = a5 * inv + b1v.y;
        o1v.z = a6 * inv + b1v.z; o1v.w = a7 * inv + b1v.w;
        if (VAL_RES) {
            // residual = relu(val0[d][head]*W0s[c]+bias0[c]) (bit-identical to xa)
            float vv = val0[d * 4 + head];
            float4 wa = ((const float4*)W0s)[2 * l16];
            float4 wb = ((const float4*)W0s)[2 * l16 + 1];
            float4 ba = ((const float4*)bias0)[2 * l16];
            float4 bb = ((const float4*)bias0)[2 * l16 + 1];
            o0v.x += fmaxf(fmaf(vv, wa.x, ba.x), 0.f);
            o0v.y += fmaxf(fmaf(vv, wa.y, ba.y), 0.f);
            o0v.z += fmaxf(fmaf(vv, wa.z, ba.z), 0.f);
            o0v.w += fmaxf(fmaf(vv, wa.w, ba.w), 0.f);
            o1v.x += fmaxf(fmaf(vv, wb.x, bb.x), 0.f);
            o1v.y += fmaxf(fmaf(vv, wb.y, bb.y), 0.f);
            o1v.z += fmaxf(fmaf(vv, wb.z, bb.z), 0.f);
            o1v.w += fmaxf(fmaf(vv, wb.w, bb.w), 0.f);
        } else if (RES_BF16) {
            uint4 pk = ((const uint4*)x_prev)[(size_t)d * 16 + l16];
            o0v.x += __uint_as_float(pk.x << 16);
            o0v.y += __uint_as_float(pk.x & 0xFFFF0000u);
            o0v.z += __uint_as_float(pk.y << 16);
            o0v.w += __uint_as_float(pk.y & 0xFFFF0000u);
            o1v.x += __uint_as_float(pk.z << 16);
            o1v.y += __uint_as_float(pk.z & 0xFFFF0000u);
            o1v.z += __uint_as_float(pk.w << 16);
            o1v.w += __uint_as_float(pk.w & 0xFFFF0000u);
        } else if (x_prev) {
            float4 p0 = ((const float4*)x_prev)[(size_t)d * 32 + 2 * l16];
            float4 p1 = ((const float4*)x_prev)[(size_t)d * 32 + 2 * l16 + 1];
            o0v.x += p0.x; o0v.y += p0.y; o0v.z += p0.z; o0v.w += p0.w;
            o1v.x += p1.x; o1v.y += p1.y; o1v.z += p1.z; o1v.w += p1.w;
        }
        o0v.x = fmaxf(o0v.x, 0.f); o0v.y = fmaxf(o0v.y, 0.f);
        o0v.z = fmaxf(o0v.z, 0.f); o0v.w = fmaxf(o0v.w, 0.f);
        o1v.x = fmaxf(o1v.x, 0.f); o1v.y = fmaxf(o1v.y, 0.f);
        o1v.z = fmaxf(o1v.z, 0.f); o1v.w = fmaxf(o1v.w, 0.f);
        if (OUT_BF16) {
            uint4 pk;
            pk.x = pack_bf2(o0v.x, o0v.y);
            pk.y = pack_bf2(o0v.z, o0v.w);
            pk.z = pack_bf2(o1v.x, o1v.y);
            pk.w = pack_bf2(o1v.z, o1v.w);
            ((uint4*)x_out)[(size_t)d * 16 + l16] = pk;
        } else {
            ((float4*)x_out)[(size_t)d * 32 + 2 * l16]     = o0v;
            ((float4*)x_out)[(size_t)d * 32 + 2 * l16 + 1] = o1v;
        }
    }
}

// ---------------------------------------------------------------------------
// MLP head via MFMA, bf16 input rows: 7 col-tiles (hidden >=100 zero-padded).
__global__ __launch_bounds__(256, 2) void mlp_kernel(
    const unsigned short* __restrict__ Xbf, const unsigned* __restrict__ W1q,
    const float* __restrict__ b1, const float* __restrict__ W2,
    const float* __restrict__ b2, float* __restrict__ out, int n) {
    int tid = threadIdx.x;
    int lane = tid & 63;
    int wv = tid >> 6;
    int q = lane >> 4, nl = lane & 15;
    int row_blk = blockIdx.x * 64;
    int wrow = wv * 16;

    int arow = row_blk + wrow + nl;
    if (arow >= n) arow = n - 1;
    const uint4* Xr = (const uint4*)(Xbf + (size_t)arow * HCONC);

    f32x4 acc[7];
#pragma unroll
    for (int t = 0; t < 7; t++) acc[t] = (f32x4){0.f, 0.f, 0.f, 0.f};

    const uint4* Wp4 = (const uint4*)W1q;
#pragma unroll
    for (int kb = 0; kb < 4; kb++) {
        uint4 ua = Xr[kb * 4 + q];            // channels 32kb+8q .. +7 (bf16)
        bf16x8 af = __builtin_bit_cast(bf16x8, ua);
#pragma unroll
        for (int t = 0; t < 7; t++) {
            uint4 ub = Wp4[(t * 4 + kb) * 64 + lane];
            bf16x8 bf = __builtin_bit_cast(bf16x8, ub);
            acc[t] = __builtin_amdgcn_mfma_f32_16x16x32_bf16(af, bf, acc[t], 0, 0, 0);
        }
    }

    float b1c[7], w2c[7];
#pragma unroll
    for (int t = 0; t < 7; t++) {
        int c = 16 * t + nl;
        bool vld = c < 100;
        b1c[t] = vld ? b1[c] : 0.f;
        w2c[t] = vld ? W2[c] : 0.f;
    }
    float b2v = b2[0];

#pragma unroll
    for (int reg = 0; reg < 4; reg++) {
        float sum = 0.f;
#pragma unroll
        for (int t = 0; t < 7; t++) {
            float hv = fmaxf(acc[t][reg] + b1c[t], 0.f);
            sum = fmaf(hv, w2c[t], sum);
        }
#pragma unroll
        for (int off = 1; off <= 8; off <<= 1)
            sum += __shfl_xor(sum, off);
        int row = row_blk + wrow + q * 4 + reg;
        if (nl == 0 && row < n)
            out[row] = 1.f / (1.f + __expf(-(sum + b2v)));
    }
}

// ---------------------------------------------------------------------------
extern "C" void kernel_launch(void* const* d_in, const int* in_sizes, int n_in,
                              void* d_out, int out_size, void* d_ws, size_t ws_size,
                              hipStream_t stream) {
    const float* x       = (const float*)d_in[0];
    const int*   ei      = (const int*)d_in[1];     // [2,E]: src then dst
    const int*   etype   = (const int*)d_in[2];
    const float* emb     = (const float*)d_in[3];   // [16,8]
    const float* W_l0    = (const float*)d_in[4];   // [32,128]
    const float* W_l1    = (const float*)d_in[5];   // [128,128]
    const float* W_l2    = (const float*)d_in[6];   // [128,128]
    const float* att_src = (const float*)d_in[7];   // [3,4,32]
    const float* att_dst = (const float*)d_in[8];
    const float* att_edge= (const float*)d_in[9];
    const float* W_edge  = (const float*)d_in[10];  // [3,8,128]
    const float* bias    = (const float*)d_in[11];  // [3,128]
    const float* mW1     = (const float*)d_in[12];  // [128,100]
    const float* mb1     = (const float*)d_in[13];
    const float* mW2     = (const float*)d_in[14];  // [100,1]
    const float* mb2     = (const float*)d_in[15];

    int n = in_sizes[0];   // 50000
    int E = in_sizes[2];   // 800000
    int nbuk = (n + 255) >> 8;   // 196
    int nA = (E + TILE - 1) / TILE;   // 391

    // workspace carve (keep 16-byte alignment for uint4 views)
    float* p   = (float*)d_ws;
    float* xa  = p; p += (size_t)n * HCONC;        // bf16 rows (agg2 out)
    float* xb  = p; p += (size_t)n * HCONC;        // bf16 rows (agg1 out)
    float* ssrc = p; p += (size_t)n * NHEAD;
    float* sdst = p; p += (size_t)n * NHEAD;
    float* val0 = p; p += (size_t)n * NHEAD;       // layer-0 rank-1 output
    float* hbf  = p; p += (size_t)n * 32;          // fp8 h buffer (n*128 bytes)
    unsigned* Wl1q = (unsigned*)p; p += 8192;      // MFMA-B-packed W_l1
    unsigned* Wl2q = (unsigned*)p; p += 8192;      // MFMA-B-packed W_l2
    unsigned* W1q  = (unsigned*)p; p += 7168;      // MFMA-B-packed mW1 (7 tiles)
    int* row_ptr     = (int*)p;
    int* gcursor     = row_ptr + n + 1;
    int* cnt         = gcursor + 256;
    float* W0s    = (float*)(cnt + 16);
    float* SA0    = W0s + HCONC;
    float* SD0    = SA0 + NHEAD;
    float* meanat = SD0 + NHEAD;     // unused (kept for layout stability)
    float* stab   = meanat + EDIM;   // 3*68 = 204, round to 256
    char* raw = (char*)(stab + 256);
    unsigned* ebuf = (unsigned*)(((uintptr_t)raw + 15) & ~(uintptr_t)15); // nbuk*BCAP u32
    unsigned* col = ebuf + (size_t)nbuk * BCAP;                          // E entries

    // CSR build: memset cursors -> binA (binning + weight pack + setup riding
    // along) -> binB (fine sort + fused layer-0 -> val0 only)
    hipMemsetAsync(gcursor, 0, (256 + 16) * sizeof(int), stream);
    binA_kernel<<<nA + 93, 256, 0, stream>>>(ei, etype, E, nbuk, nA, gcursor, cnt,
                                             ebuf, W_l1, W_l2, mW1, Wl1q, Wl2q, W1q,
                                             W_l0, emb, att_src, att_dst, att_edge,
                                             W_edge, W0s, SA0, SD0, stab);
    binB_kernel<<<nbuk, 256, 0, stream>>>(ebuf, gcursor, n, nbuk, row_ptr, col,
                                          cnt, stab, E, x, SA0, SD0, val0);

    // layer 1: transform reconstructs rows from val0 (no xa materialization);
    // agg1 emits bf16 rows (xb)
    transform0_kernel<<<(n + 63) / 64, 256, 0, stream>>>(val0, W0s, bias + 0, Wl1q,
                                                         att_src + 128, att_dst + 128,
                                                         (unsigned short*)hbf, ssrc, sdst, n);
    agg_kernel<true, true, false><<<(n + 3) / 4, 256, 0, stream>>>(
        (const unsigned char*)hbf, ssrc, sdst, row_ptr, col,
        stab + 68, bias + 128, nullptr, val0, W0s, bias + 0, xb, n);
    // layer 2: transform reads bf16 rows; agg2 residual from bf16 xb; bf16 out
    transform_kernel<<<(n + 63) / 64, 256, 0, stream>>>((const unsigned short*)xb, Wl2q,
                                                        att_src + 256, att_dst + 256,
                                                        (unsigned short*)hbf, ssrc, sdst, n);
    agg_kernel<false, true, true><<<(n + 3) / 4, 256, 0, stream>>>(
        (const unsigned char*)hbf, ssrc, sdst, row_ptr, col,
        stab + 136, bias + 256, xb, nullptr, nullptr, nullptr, xa, n);
    // MLP head (MFMA, bf16 input)
    mlp_kernel<<<(n + 63) / 64, 256, 0, stream>>>((const unsigned short*)xa, W1q,
                                                  mb1, mW2, mb2, (float*)d_out, n);
}

// Round 4
// 220.374 us; speedup vs baseline: 1.1877x; 1.0995x over previous
//
#include <hip/hip_runtime.h>
#include <hip/hip_bf16.h>
#include <hip/hip_fp16.h>

#define HCONC 128   // H*C
#define NHEAD 4
#define CCH   32
#define EDIM  8
#define NREL  16
#define BCAP  5120  // per-bucket capacity (mean ~4081, +16 sigma headroom)
#define TILE  2048  // edges per binA block

typedef float floatx2 __attribute__((ext_vector_type(2)));
typedef short bf16x8 __attribute__((ext_vector_type(8)));
typedef float f32x4 __attribute__((ext_vector_type(4)));

__device__ inline unsigned short pack_fp8x2(float a, float b) {
    return (unsigned short)(__builtin_amdgcn_cvt_pk_fp8_f32(a, b, 0, false) & 0xFFFF);
}
__device__ inline unsigned pack_bf2(float lo, float hi) {
    __hip_bfloat162 v;
    v.x = __float2bfloat16(lo);
    v.y = __float2bfloat16(hi);
    return *(unsigned*)&v;
}

// ---------------------------------------------------------------------------
// binA: tile-local counting sort by dst-bucket, coalesced run writes.
// Blocks [nA, nA+92): MFMA weight packing.  Block nA+92: setup.
// Cursors are RELATIVE (zero-initialized by a tiny memset before launch).
// ebuf record: src(16) | typ(4)<<16 | (dst&255)<<20  -- bucket implicit.
__global__ __launch_bounds__(256) void binA_kernel(
    const int* __restrict__ ei, const int* __restrict__ etype, int E, int nbuk, int nA,
    int* __restrict__ gcursor, int* __restrict__ cnt, unsigned* __restrict__ ebuf,
    const float* __restrict__ W_l1, const float* __restrict__ W_l2,
    const float* __restrict__ mW1,
    unsigned* __restrict__ Wl1q, unsigned* __restrict__ Wl2q, unsigned* __restrict__ W1q,
    const float* __restrict__ W_l0, const float* __restrict__ emb,
    const float* __restrict__ att_src, const float* __restrict__ att_dst,
    const float* __restrict__ att_edge, const float* __restrict__ W_edge,
    float* __restrict__ W0s, float* __restrict__ SA0, float* __restrict__ SD0,
    float* __restrict__ stab) {
    __shared__ int hist[256], lbase[256], gbase[256], tmp[256];
    __shared__ int lcnt16[NREL];
    __shared__ unsigned srt[TILE];
    __shared__ unsigned char sbuk[TILE];
    __shared__ float W0s_s[HCONC];
    int t = threadIdx.x;

    if ((int)blockIdx.x >= nA) {               // ---- pack / setup blocks ----
        int pb = (int)blockIdx.x - nA;
        if (pb == 92) {                        // setup (weights only; no cnt dep)
            if (t < HCONC) {
                float s = 0.f;
                for (int k = 0; k < CCH; k++) s += W_l0[k * HCONC + t];
                W0s[t] = s; W0s_s[t] = s;
            }
            __syncthreads();
            if (t < NHEAD) {
                float sa = 0.f, sd = 0.f;
                for (int c = 0; c < CCH; c++) {
                    sa += W0s_s[t * CCH + c] * att_src[t * CCH + c];
                    sd += W0s_s[t * CCH + c] * att_dst[t * CCH + c];
                }
                SA0[t] = sa; SD0[t] = sd;
            }
            if (t < 192) {                     // 3 layers x 16 types x 4 heads
                int l = t >> 6, rem = t & 63, typ = rem >> 2, hh = rem & 3;
                const float* attr = emb + typ * EDIM;
                const float* We = W_edge + l * EDIM * HCONC;
                const float* ae = att_edge + l * HCONC + hh * CCH;
                float s = 0.f;
                for (int c = 0; c < CCH; c++) {
                    float ev = 0.f;
                    for (int dd = 0; dd < EDIM; dd++)
                        ev += attr[dd] * We[dd * HCONC + hh * CCH + c];
                    s += ev * ae[c];
                }
                stab[l * 68 + typ * 4 + hh] = s;   // mean entries filled by binB b==0
            }
            return;
        }
        int i = pb * 256 + t;
        if (i < 16384) {                       // MFMA B-pack (W_l1 then W_l2)
            const float* W = (i < 8192) ? W_l1 : W_l2;
            unsigned* dst = (i < 8192) ? Wl1q : Wl2q;
            int r = i & 8191;
            int j2 = r & 3, lane = (r >> 2) & 63, kb = (r >> 8) & 3, tt = r >> 10;
            int k0 = kb * 32 + ((lane >> 4) & 3) * 8 + 2 * j2;
            int c = 16 * tt + (lane & 15);
            dst[r] = pack_bf2(W[k0 * 128 + c], W[(k0 + 1) * 128 + c]);
        } else if (i < 16384 + 7168) {         // mlp W1 B-pack, 7 tiles
            int r = i - 16384;
            int j2 = r & 3, lane = (r >> 2) & 63, kb = (r >> 8) & 3, tt = r >> 10;
            int k0 = kb * 32 + ((lane >> 4) & 3) * 8 + 2 * j2;
            int c = 16 * tt + (lane & 15);
            float lo = (c < 100) ? mW1[k0 * 100 + c] : 0.f;
            float hi = (c < 100) ? mW1[(k0 + 1) * 100 + c] : 0.f;
            W1q[r] = pack_bf2(lo, hi);
        }
        return;
    }

    // ---- edge binning ----
    hist[t] = 0;
    if (t < NREL) lcnt16[t] = 0;
    __syncthreads();

    int base = blockIdx.x * TILE;
    int count = min(TILE, E - base);

    unsigned rec[8]; int slot[8]; int buk[8];
#pragma unroll
    for (int i = 0; i < 8; i++) {
        int idx = t + i * 256;
        if (idx < count) {
            int g = base + idx;
            int s = ei[g], d = ei[E + g], ty = etype[g];
            rec[i] = (unsigned)s | ((unsigned)ty << 16) | ((unsigned)(d & 255) << 20);
            buk[i] = d >> 8;
            slot[i] = atomicAdd(&hist[buk[i]], 1);
            atomicAdd(&lcnt16[ty], 1);
        } else buk[i] = -1;
    }
    __syncthreads();

    int v = hist[t];
    tmp[t] = v; __syncthreads();
    for (int off = 1; off < 256; off <<= 1) {
        int add = (t >= off) ? tmp[t - off] : 0; __syncthreads();
        tmp[t] += add; __syncthreads();
    }
    lbase[t] = tmp[t] - v;
    if (t < nbuk && v > 0) gbase[t] = atomicAdd(&gcursor[t], v);  // relative reserve
    __syncthreads();

#pragma unroll
    for (int i = 0; i < 8; i++)
        if (buk[i] >= 0) {
            int pos = lbase[buk[i]] + slot[i];
            srt[pos] = rec[i];
            sbuk[pos] = (unsigned char)buk[i];
        }
    if (t < NREL) atomicAdd(&cnt[t], lcnt16[t]);
    __syncthreads();

    for (int idx = t; idx < count; idx += 256) {
        unsigned r = srt[idx];
        int bk = sbuk[idx];
        int rel = gbase[bk] + idx - lbase[bk];
        if (rel < BCAP) ebuf[bk * BCAP + rel] = r;   // cap guard (never trips)
    }
}

// ---------------------------------------------------------------------------
// binB: per-bucket fine sort + FUSED layer-0 aggregation -> val0[n][4] only
// (rank-1 layer-0 output; consumers reconstruct rows on the fly).
__global__ __launch_bounds__(256) void binB_kernel(
    const unsigned* __restrict__ ebuf, const int* __restrict__ gcursor,
    int n, int nbuk,
    int* __restrict__ row_ptr, unsigned* __restrict__ col,
    const int* __restrict__ cnt, float* __restrict__ stab, int E,
    const float* __restrict__ x,
    const float* __restrict__ SA0, const float* __restrict__ SD0,
    float* __restrict__ val0) {
    __shared__ int hist[256], lcur[256], tmp[256];
    __shared__ unsigned colsl[BCAP];            // 20 KB
    __shared__ __align__(16) float stab0[68];
    int b = blockIdx.x, t = threadIdx.x;

    if (t < 64) stab0[t] = stab[t];             // layer-0 per-type entries
    float invE = 1.f / (float)E;
    if (t < 4) {                                // local layer-0 mean entry
        float s = 0.f;
        for (int r = 0; r < NREL; r++) s += (float)cnt[r] * stab[r * 4 + t];
        stab0[64 + t] = s * invE;
    }

    // inline bucket-base scan (gcursor holds per-bucket sizes)
    int c = (t < nbuk) ? gcursor[t] : 0;
    tmp[t] = c; __syncthreads();
    for (int off = 1; off < 256; off <<= 1) {
        int add = (t >= off) ? tmp[t - off] : 0; __syncthreads();
        tmp[t] += add; __syncthreads();
    }
    int gstart = (b == 0) ? 0 : tmp[b - 1];
    if (b == 0 && t == nbuk - 1) row_ptr[n] = tmp[t];   // total edge count
    if (b == 0 && t < 12) {                     // global mean entries, layers 0-2
        int l = t >> 2, hh = t & 3;
        float s = 0.f;
        for (int r = 0; r < NREL; r++) s += (float)cnt[r] * stab[l * 68 + r * 4 + hh];
        stab[l * 68 + 64 + hh] = s * invE;
    }
    __syncthreads();

    int bbase = b * BCAP;
    int cntb = min(gcursor[b], BCAP);
    hist[t] = 0;
    __syncthreads();
    for (int i = t; i < cntb; i += 256) {
        unsigned r = ebuf[bbase + i];
        atomicAdd(&hist[r >> 20], 1);
    }
    __syncthreads();
    int v = hist[t];
    tmp[t] = v; __syncthreads();
    for (int off = 1; off < 256; off <<= 1) {
        int add = (t >= off) ? tmp[t - off] : 0; __syncthreads();
        tmp[t] += add; __syncthreads();
    }
    lcur[t] = tmp[t] - v;
    int gdst = (b << 8) + t;
    if (gdst < n) row_ptr[gdst] = gstart + tmp[t] - v;
    __syncthreads();
    for (int i = t; i < cntb; i += 256) {
        unsigned r = ebuf[bbase + i];
        int pos = atomicAdd(&lcur[r >> 20], 1);
        colsl[pos] = r & 0xFFFFFu;              // src | typ<<16
    }
    __syncthreads();
    for (int i = t; i < cntb; i += 256)
        col[gstart + i] = colsl[i];

    // ---- fused layer-0 aggregation (h0 is rank-1: per-(dst,head) scalar) ----
    int lo = tmp[t] - v, hi = tmp[t];           // this dst's range in colsl
    if (gdst < n) {
        float xd = x[gdst];
        float4 sa4 = *(const float4*)SA0;
        float4 sdc = *(const float4*)SD0;
        float sd0 = xd * sdc.x, sd1 = xd * sdc.y, sd2 = xd * sdc.z, sd3 = xd * sdc.w;
        // self edge (typ=16 -> mean attr)
        float s0 = fmaf(xd, sa4.x, sd0) + stab0[64];
        float s1 = fmaf(xd, sa4.y, sd1) + stab0[65];
        float s2 = fmaf(xd, sa4.z, sd2) + stab0[66];
        float s3 = fmaf(xd, sa4.w, sd3) + stab0[67];
        s0 = s0 > 0.f ? s0 : 0.2f * s0;
        s1 = s1 > 0.f ? s1 : 0.2f * s1;
        s2 = s2 > 0.f ? s2 : 0.2f * s2;
        s3 = s3 > 0.f ? s3 : 0.2f * s3;
        float w0 = __expf(s0), w1 = __expf(s1), w2 = __expf(s2), w3 = __expf(s3);
        float den0 = w0, den1 = w1, den2 = w2, den3 = w3;
        float sx0 = w0 * xd, sx1 = w1 * xd, sx2 = w2 * xd, sx3 = w3 * xd;
        for (int j = lo; j < hi; j++) {
            unsigned p = colsl[j];
            float xv = x[p & 0xFFFFu];
            int typ = (int)(p >> 16);
            float4 st = *(const float4*)&stab0[typ * 4];
            float e0 = fmaf(xv, sa4.x, sd0) + st.x;
            float e1 = fmaf(xv, sa4.y, sd1) + st.y;
            float e2 = fmaf(xv, sa4.z, sd2) + st.z;
            float e3 = fmaf(xv, sa4.w, sd3) + st.w;
            e0 = e0 > 0.f ? e0 : 0.2f * e0;
            e1 = e1 > 0.f ? e1 : 0.2f * e1;
            e2 = e2 > 0.f ? e2 : 0.2f * e2;
            e3 = e3 > 0.f ? e3 : 0.2f * e3;
            float g0 = __expf(e0), g1 = __expf(e1), g2 = __expf(e2), g3 = __expf(e3);
            den0 += g0; den1 += g1; den2 += g2; den3 += g3;
            sx0 = fmaf(g0, xv, sx0); sx1 = fmaf(g1, xv, sx1);
            sx2 = fmaf(g2, xv, sx2); sx3 = fmaf(g3, xv, sx3);
        }
        float4 vo;
        vo.x = sx0 / (den0 + 1e-16f);
        vo.y = sx1 / (den1 + 1e-16f);
        vo.z = sx2 / (den2 + 1e-16f);
        vo.w = sx3 / (den3 + 1e-16f);
        ((float4*)val0)[gdst] = vo;
    }
}

// ---------------------------------------------------------------------------
// Layer-1 transform: A rows reconstructed in-register from val0 (rank-1 layer-0
// output), B = MFMA-packed W_l1.  Bit-identical to reading the materialized xa.
__global__ __launch_bounds__(256, 2) void transform0_kernel(
    const float* __restrict__ val0, const float* __restrict__ W0s,
    const float* __restrict__ bias0, const unsigned* __restrict__ Wq,
    const float* __restrict__ a_src, const float* __restrict__ a_dst,
    unsigned short* __restrict__ h8, float* __restrict__ s_src,
    float* __restrict__ s_dst, int n) {
    __shared__ unsigned short hs[64 * 128];   // 16 KB epilogue transpose
    int tid = threadIdx.x;
    int lane = tid & 63;
    int wv = tid >> 6;
    int q = lane >> 4, nl = lane & 15;
    int row_blk = blockIdx.x * 64;
    int wrow = wv * 16;

    int arow = row_blk + wrow + nl;
    if (arow >= n) arow = n - 1;              // clamp; stores are guarded
    float4 v4 = ((const float4*)val0)[arow];

    f32x4 acc[8];
#pragma unroll
    for (int t = 0; t < 8; t++) acc[t] = (f32x4){0.f, 0.f, 0.f, 0.f};

    const uint4* Wp4 = (const uint4*)Wq;
#pragma unroll
    for (int kb = 0; kb < 4; kb++) {
        int c4 = 8 * kb + 2 * q;              // float4 index of channel block
        float4 wa = ((const float4*)W0s)[c4];
        float4 wb = ((const float4*)W0s)[c4 + 1];
        float4 ba = ((const float4*)bias0)[c4];
        float4 bb = ((const float4*)bias0)[c4 + 1];
        float vr = kb == 0 ? v4.x : kb == 1 ? v4.y : kb == 2 ? v4.z : v4.w;
        float x0 = fmaxf(fmaf(vr, wa.x, ba.x), 0.f);
        float x1 = fmaxf(fmaf(vr, wa.y, ba.y), 0.f);
        float x2 = fmaxf(fmaf(vr, wa.z, ba.z), 0.f);
        float x3 = fmaxf(fmaf(vr, wa.w, ba.w), 0.f);
        float x4 = fmaxf(fmaf(vr, wb.x, bb.x), 0.f);
        float x5 = fmaxf(fmaf(vr, wb.y, bb.y), 0.f);
        float x6 = fmaxf(fmaf(vr, wb.z, bb.z), 0.f);
        float x7 = fmaxf(fmaf(vr, wb.w, bb.w), 0.f);
        uint4 ua;
        ua.x = pack_bf2(x0, x1);
        ua.y = pack_bf2(x2, x3);
        ua.z = pack_bf2(x4, x5);
        ua.w = pack_bf2(x6, x7);
        bf16x8 af = __builtin_bit_cast(bf16x8, ua);
#pragma unroll
        for (int t = 0; t < 8; t++) {
            uint4 ub = Wp4[(t * 4 + kb) * 64 + lane];
            bf16x8 bf = __builtin_bit_cast(bf16x8, ub);
            acc[t] = __builtin_amdgcn_mfma_f32_16x16x32_bf16(af, bf, acc[t], 0, 0, 0);
        }
    }

    // scores: lane holds col c=16t+nl of rows wrow+q*4+reg
    float av[8], dv[8];
#pragma unroll
    for (int t = 0; t < 8; t++) {
        av[t] = a_src[16 * t + nl];
        dv[t] = a_dst[16 * t + nl];
    }
#pragma unroll
    for (int reg = 0; reg < 4; reg++) {
        float t0 = acc[0][reg] * av[0] + acc[1][reg] * av[1];
        float t1 = acc[2][reg] * av[2] + acc[3][reg] * av[3];
        float t2 = acc[4][reg] * av[4] + acc[5][reg] * av[5];
        float t3 = acc[6][reg] * av[6] + acc[7][reg] * av[7];
        float d0 = acc[0][reg] * dv[0] + acc[1][reg] * dv[1];
        float d1 = acc[2][reg] * dv[2] + acc[3][reg] * dv[3];
        float d2 = acc[4][reg] * dv[4] + acc[5][reg] * dv[5];
        float d3 = acc[6][reg] * dv[6] + acc[7][reg] * dv[7];
#pragma unroll
        for (int off = 1; off <= 8; off <<= 1) {
            t0 += __shfl_xor(t0, off); t1 += __shfl_xor(t1, off);
            t2 += __shfl_xor(t2, off); t3 += __shfl_xor(t3, off);
            d0 += __shfl_xor(d0, off); d1 += __shfl_xor(d1, off);
            d2 += __shfl_xor(d2, off); d3 += __shfl_xor(d3, off);
        }
        int row = row_blk + wrow + q * 4 + reg;
        if (row < n && nl < 4) {
            float ts = nl == 0 ? t0 : nl == 1 ? t1 : nl == 2 ? t2 : t3;
            float td = nl == 0 ? d0 : nl == 1 ? d1 : nl == 2 ? d2 : d3;
            s_src[row * 4 + nl] = ts;
            s_dst[row * 4 + nl] = td;
        }
    }

    // h8: transpose acc through LDS (bf16) then pack fp8 coalesced
#pragma unroll
    for (int t = 0; t < 8; t++) {
#pragma unroll
        for (int reg = 0; reg < 4; reg++) {
            __hip_bfloat16 b = __float2bfloat16(acc[t][reg]);
            hs[(wrow + q * 4 + reg) * 128 + 16 * t + nl] = *(unsigned short*)&b;
        }
    }
    __syncthreads();
    const unsigned* hsu = (const unsigned*)hs;
#pragma unroll
    for (int i = 0; i < 16; i++) {
        int pidx = tid + i * 256;             // channel-pair index in 64x64
        int rl = pidx >> 6, cp = pidx & 63;
        int row = row_blk + rl;
        if (row < n) {
            unsigned u = hsu[rl * 64 + cp];
            float f0 = __uint_as_float(u << 16);
            float f1 = __uint_as_float(u & 0xFFFF0000u);
            h8[(size_t)row * 64 + cp] = pack_fp8x2(f0, f1);
        }
    }
}

// ---------------------------------------------------------------------------
// Dense transform via MFMA, bf16 input rows (layer 2: xb is stored bf16 —
// bit-identical to the old f32 path since MFMA consumed bf16-rounded values).
__global__ __launch_bounds__(256, 2) void transform_kernel(
    const unsigned short* __restrict__ Xbf, const unsigned* __restrict__ Wq,
    const float* __restrict__ a_src, const float* __restrict__ a_dst,
    unsigned short* __restrict__ h8, float* __restrict__ s_src,
    float* __restrict__ s_dst, int n) {
    __shared__ unsigned short hs[64 * 128];   // 16 KB epilogue transpose
    int tid = threadIdx.x;
    int lane = tid & 63;
    int wv = tid >> 6;
    int q = lane >> 4, nl = lane & 15;
    int row_blk = blockIdx.x * 64;
    int wrow = wv * 16;

    int arow = row_blk + wrow + nl;
    if (arow >= n) arow = n - 1;              // clamp; stores are guarded
    const uint4* Xr = (const uint4*)(Xbf + (size_t)arow * HCONC);

    f32x4 acc[8];
#pragma unroll
    for (int t = 0; t < 8; t++) acc[t] = (f32x4){0.f, 0.f, 0.f, 0.f};

    const uint4* Wp4 = (const uint4*)Wq;
#pragma unroll
    for (int kb = 0; kb < 4; kb++) {
        uint4 ua = Xr[kb * 4 + q];            // channels 32kb+8q .. +7 (bf16)
        bf16x8 af = __builtin_bit_cast(bf16x8, ua);
#pragma unroll
        for (int t = 0; t < 8; t++) {
            uint4 ub = Wp4[(t * 4 + kb) * 64 + lane];
            bf16x8 bf = __builtin_bit_cast(bf16x8, ub);
            acc[t] = __builtin_amdgcn_mfma_f32_16x16x32_bf16(af, bf, acc[t], 0, 0, 0);
        }
    }

    // scores: lane holds col c=16t+nl of rows wrow+q*4+reg
    float av[8], dv[8];
#pragma unroll
    for (int t = 0; t < 8; t++) {
        av[t] = a_src[16 * t + nl];
        dv[t] = a_dst[16 * t + nl];
    }
#pragma unroll
    for (int reg = 0; reg < 4; reg++) {
        float t0 = acc[0][reg] * av[0] + acc[1][reg] * av[1];
        float t1 = acc[2][reg] * av[2] + acc[3][reg] * av[3];
        float t2 = acc[4][reg] * av[4] + acc[5][reg] * av[5];
        float t3 = acc[6][reg] * av[6] + acc[7][reg] * av[7];
        float d0 = acc[0][reg] * dv[0] + acc[1][reg] * dv[1];
        float d1 = acc[2][reg] * dv[2] + acc[3][reg] * dv[3];
        float d2 = acc[4][reg] * dv[4] + acc[5][reg] * dv[5];
        float d3 = acc[6][reg] * dv[6] + acc[7][reg] * dv[7];
#pragma unroll
        for (int off = 1; off <= 8; off <<= 1) {
            t0 += __shfl_xor(t0, off); t1 += __shfl_xor(t1, off);
            t2 += __shfl_xor(t2, off); t3 += __shfl_xor(t3, off);
            d0 += __shfl_xor(d0, off); d1 += __shfl_xor(d1, off);
            d2 += __shfl_xor(d2, off); d3 += __shfl_xor(d3, off);
        }
        int row = row_blk + wrow + q * 4 + reg;
        if (row < n && nl < 4) {
            float ts = nl == 0 ? t0 : nl == 1 ? t1 : nl == 2 ? t2 : t3;
            float td = nl == 0 ? d0 : nl == 1 ? d1 : nl == 2 ? d2 : d3;
            s_src[row * 4 + nl] = ts;
            s_dst[row * 4 + nl] = td;
        }
    }

    // h8: transpose acc through LDS (bf16) then pack fp8 coalesced
#pragma unroll
    for (int t = 0; t < 8; t++) {
#pragma unroll
        for (int reg = 0; reg < 4; reg++) {
            __hip_bfloat16 b = __float2bfloat16(acc[t][reg]);
            hs[(wrow + q * 4 + reg) * 128 + 16 * t + nl] = *(unsigned short*)&b;
        }
    }
    __syncthreads();
    const unsigned* hsu = (const unsigned*)hs;
#pragma unroll
    for (int i = 0; i < 16; i++) {
        int pidx = tid + i * 256;             // channel-pair index in 64x64
        int rl = pidx >> 6, cp = pidx & 63;
        int row = row_blk + rl;
        if (row < n) {
            unsigned u = hsu[rl * 64 + cp];
            float f0 = __uint_as_float(u << 16);
            float f1 = __uint_as_float(u & 0xFFFF0000u);
            h8[(size_t)row * 64 + cp] = pack_fp8x2(f0, f1);
        }
    }
}

// ---------------------------------------------------------------------------
// Softmax-aggregation v3: one dst per 16-lane group (4 dsts/wave, 16/block).
// Each lane owns 8 fp8 channels of its group's dst and computes its own head's
// score per edge (exp recomputed 4x/head-lane-group) -- this removes ALL
// shuffles (score broadcast + 18-op xor merge) at identical gather volume:
// group reads the 128B h8 row as consecutive uint2, s_src as 4x broadcast
// scalars, col[e] sequentially (16 edges per cache line).
// VAL_RES: residual reconstructed from val0 (layer 1).  RES_BF16: residual
// read from bf16 rows (layer 2; xb stored bf16).  OUT_BF16: emit bf16 rows.
template <bool VAL_RES, bool OUT_BF16, bool RES_BF16>
__global__ __launch_bounds__(256) void agg_kernel(
    const unsigned char* __restrict__ h8,   // fp8 e4m3, [n][128]
    const float* __restrict__ s_src, const float* __restrict__ s_dst,
    const int* __restrict__ row_ptr, const unsigned* __restrict__ col,
    const float* __restrict__ tab, const float* __restrict__ bias,
    const void* __restrict__ x_prev,
    const float* __restrict__ val0, const float* __restrict__ W0s,
    const float* __restrict__ bias0,
    void* __restrict__ x_out, int n) {
    __shared__ __align__(16) float stab_s[68];
    if (threadIdx.x < 68) stab_s[threadIdx.x] = tab[threadIdx.x];
    __syncthreads();

    int tid = threadIdx.x;
    int lane = tid & 63;
    int grp = lane >> 4;              // 4 groups per wave
    int l16 = lane & 15;              // channel octet within row
    int head = l16 >> 2;              // 4 lanes per head
    int d = blockIdx.x * 16 + (tid >> 6) * 4 + grp;
    if (d >= n) return;

    int start = row_ptr[d], end = row_ptr[d + 1];
    float sdh = s_dst[d * 4 + head];

    // self edge (typ=16, mean attr)
    float s = s_src[d * 4 + head] + sdh + stab_s[64 + head];
    s = s > 0.f ? s : 0.2f * s;
    float w = __expf(s);
    uint2 u = ((const uint2*)(h8 + (size_t)d * 128))[l16];
    floatx2 f01 = __builtin_amdgcn_cvt_pk_f32_fp8((int)u.x, false);
    floatx2 f23 = __builtin_amdgcn_cvt_pk_f32_fp8((int)u.x, true);
    floatx2 f45 = __builtin_amdgcn_cvt_pk_f32_fp8((int)u.y, false);
    floatx2 f67 = __builtin_amdgcn_cvt_pk_f32_fp8((int)u.y, true);
    float den = w;
    float a0 = w * f01.x, a1 = w * f01.y;
    float a2 = w * f23.x, a3 = w * f23.y;
    float a4 = w * f45.x, a5 = w * f45.y;
    float a6 = w * f67.x, a7 = w * f67.y;

#pragma unroll 4
    for (int e = start; e < end; e++) {
        unsigned pp = col[e];                  // uniform across group
        int esrc = (int)(pp & 0xFFFFu);
        int typ = (int)(pp >> 16);
        float ss = s_src[esrc * 4 + head];     // 4-addr broadcast in group
        float sc = ss + sdh + stab_s[typ * 4 + head];
        sc = sc > 0.f ? sc : 0.2f * sc;
        float we = __expf(sc);
        uint2 ue = ((const uint2*)(h8 + (size_t)esrc * 128))[l16];
        floatx2 g01 = __builtin_amdgcn_cvt_pk_f32_fp8((int)ue.x, false);
        floatx2 g23 = __builtin_amdgcn_cvt_pk_f32_fp8((int)ue.x, true);
        floatx2 g45 = __builtin_amdgcn_cvt_pk_f32_fp8((int)ue.y, false);
        floatx2 g67 = __builtin_amdgcn_cvt_pk_f32_fp8((int)ue.y, true);
        den += we;
        a0 = fmaf(we, g01.x, a0);  a1 = fmaf(we, g01.y, a1);
        a2 = fmaf(we, g23.x, a2);  a3 = fmaf(we, g23.y, a3);
        a4 = fmaf(we, g45.x, a4);  a5 = fmaf(we, g45.y, a5);
        a6 = fmaf(we, g67.x, a6);  a7 = fmaf(we, g67.y, a7);
    }

    // epilogue: every lane writes its 8 channels of row d
    float inv = 1.f / (den + 1e-16f);
    float4 b0 = ((const float4*)bias)[2 * l16];
    float4 b1v = ((const float4*)bias)[2 * l16 + 1];
    float4 o0v, o1v;
    o0v.x = a0 * inv + b0.x;  o0v.y = a1 * inv + b0.y;
    o0v.z = a2 * inv + b0.z;  o0v.w = a3 * inv + b0.w;
    o1v.x = a4 * inv + b1v.x; o1v.y = a5 * inv + b1v.y;
    o1v.z = a6 * inv + b1v.z; o1v.w = a7 * inv + b1v.w;
    if (VAL_RES) {
        // residual = relu(val0[d][head]*W0s[c]+bias0[c]) (bit-identical to xa)
        float vv = val0[d * 4 + head];
        float4 wa = ((const float4*)W0s)[2 * l16];
        float4 wb = ((const float4*)W0s)[2 * l16 + 1];
        float4 ba = ((const float4*)bias0)[2 * l16];
        float4 bb = ((const float4*)bias0)[2 * l16 + 1];
        o0v.x += fmaxf(fmaf(vv, wa.x, ba.x), 0.f);
        o0v.y += fmaxf(fmaf(vv, wa.y, ba.y), 0.f);
        o0v.z += fmaxf(fmaf(vv, wa.z, ba.z), 0.f);
        o0v.w += fmaxf(fmaf(vv, wa.w, ba.w), 0.f);
        o1v.x += fmaxf(fmaf(vv, wb.x, bb.x), 0.f);
        o1v.y += fmaxf(fmaf(vv, wb.y, bb.y), 0.f);
        o1v.z += fmaxf(fmaf(vv, wb.z, bb.z), 0.f);
        o1v.w += fmaxf(fmaf(vv, wb.w, bb.w), 0.f);
    } else if (RES_BF16) {
        uint4 pk = ((const uint4*)x_prev)[(size_t)d * 16 + l16];
        o0v.x += __uint_as_float(pk.x << 16);
        o0v.y += __uint_as_float(pk.x & 0xFFFF0000u);
        o0v.z += __uint_as_float(pk.y << 16);
        o0v.w += __uint_as_float(pk.y & 0xFFFF0000u);
        o1v.x += __uint_as_float(pk.z << 16);
        o1v.y += __uint_as_float(pk.z & 0xFFFF0000u);
        o1v.z += __uint_as_float(pk.w << 16);
        o1v.w += __uint_as_float(pk.w & 0xFFFF0000u);
    }
    o0v.x = fmaxf(o0v.x, 0.f); o0v.y = fmaxf(o0v.y, 0.f);
    o0v.z = fmaxf(o0v.z, 0.f); o0v.w = fmaxf(o0v.w, 0.f);
    o1v.x = fmaxf(o1v.x, 0.f); o1v.y = fmaxf(o1v.y, 0.f);
    o1v.z = fmaxf(o1v.z, 0.f); o1v.w = fmaxf(o1v.w, 0.f);
    if (OUT_BF16) {
        uint4 pk;
        pk.x = pack_bf2(o0v.x, o0v.y);
        pk.y = pack_bf2(o0v.z, o0v.w);
        pk.z = pack_bf2(o1v.x, o1v.y);
        pk.w = pack_bf2(o1v.z, o1v.w);
        ((uint4*)x_out)[(size_t)d * 16 + l16] = pk;
    } else {
        ((float4*)x_out)[(size_t)d * 32 + 2 * l16]     = o0v;
        ((float4*)x_out)[(size_t)d * 32 + 2 * l16 + 1] = o1v;
    }
}

// ---------------------------------------------------------------------------
// MLP head via MFMA, bf16 input rows: 7 col-tiles (hidden >=100 zero-padded).
__global__ __launch_bounds__(256, 2) void mlp_kernel(
    const unsigned short* __restrict__ Xbf, const unsigned* __restrict__ W1q,
    const float* __restrict__ b1, const float* __restrict__ W2,
    const float* __restrict__ b2, float* __restrict__ out, int n) {
    int tid = threadIdx.x;
    int lane = tid & 63;
    int wv = tid >> 6;
    int q = lane >> 4, nl = lane & 15;
    int row_blk = blockIdx.x * 64;
    int wrow = wv * 16;

    int arow = row_blk + wrow + nl;
    if (arow >= n) arow = n - 1;
    const uint4* Xr = (const uint4*)(Xbf + (size_t)arow * HCONC);

    f32x4 acc[7];
#pragma unroll
    for (int t = 0; t < 7; t++) acc[t] = (f32x4){0.f, 0.f, 0.f, 0.f};

    const uint4* Wp4 = (const uint4*)W1q;
#pragma unroll
    for (int kb = 0; kb < 4; kb++) {
        uint4 ua = Xr[kb * 4 + q];            // channels 32kb+8q .. +7 (bf16)
        bf16x8 af = __builtin_bit_cast(bf16x8, ua);
#pragma unroll
        for (int t = 0; t < 7; t++) {
            uint4 ub = Wp4[(t * 4 + kb) * 64 + lane];
            bf16x8 bf = __builtin_bit_cast(bf16x8, ub);
            acc[t] = __builtin_amdgcn_mfma_f32_16x16x32_bf16(af, bf, acc[t], 0, 0, 0);
        }
    }

    float b1c[7], w2c[7];
#pragma unroll
    for (int t = 0; t < 7; t++) {
        int c = 16 * t + nl;
        bool vld = c < 100;
        b1c[t] = vld ? b1[c] : 0.f;
        w2c[t] = vld ? W2[c] : 0.f;
    }
    float b2v = b2[0];

#pragma unroll
    for (int reg = 0; reg < 4; reg++) {
        float sum = 0.f;
#pragma unroll
        for (int t = 0; t < 7; t++) {
            float hv = fmaxf(acc[t][reg] + b1c[t], 0.f);
            sum = fmaf(hv, w2c[t], sum);
        }
#pragma unroll
        for (int off = 1; off <= 8; off <<= 1)
            sum += __shfl_xor(sum, off);
        int row = row_blk + wrow + q * 4 + reg;
        if (nl == 0 && row < n)
            out[row] = 1.f / (1.f + __expf(-(sum + b2v)));
    }
}

// ---------------------------------------------------------------------------
extern "C" void kernel_launch(void* const* d_in, const int* in_sizes, int n_in,
                              void* d_out, int out_size, void* d_ws, size_t ws_size,
                              hipStream_t stream) {
    const float* x       = (const float*)d_in[0];
    const int*   ei      = (const int*)d_in[1];     // [2,E]: src then dst
    const int*   etype   = (const int*)d_in[2];
    const float* emb     = (const float*)d_in[3];   // [16,8]
    const float* W_l0    = (const float*)d_in[4];   // [32,128]
    const float* W_l1    = (const float*)d_in[5];   // [128,128]
    const float* W_l2    = (const float*)d_in[6];   // [128,128]
    const float* att_src = (const float*)d_in[7];   // [3,4,32]
    const float* att_dst = (const float*)d_in[8];
    const float* att_edge= (const float*)d_in[9];
    const float* W_edge  = (const float*)d_in[10];  // [3,8,128]
    const float* bias    = (const float*)d_in[11];  // [3,128]
    const float* mW1     = (const float*)d_in[12];  // [128,100]
    const float* mb1     = (const float*)d_in[13];
    const float* mW2     = (const float*)d_in[14];  // [100,1]
    const float* mb2     = (const float*)d_in[15];

    int n = in_sizes[0];   // 50000
    int E = in_sizes[2];   // 800000
    int nbuk = (n + 255) >> 8;   // 196
    int nA = (E + TILE - 1) / TILE;   // 391

    // workspace carve (keep 16-byte alignment for uint4 views)
    float* p   = (float*)d_ws;
    float* xa  = p; p += (size_t)n * HCONC;        // bf16 rows (agg2 out)
    float* xb  = p; p += (size_t)n * HCONC;        // bf16 rows (agg1 out)
    float* ssrc = p; p += (size_t)n * NHEAD;
    float* sdst = p; p += (size_t)n * NHEAD;
    float* val0 = p; p += (size_t)n * NHEAD;       // layer-0 rank-1 output
    float* hbf  = p; p += (size_t)n * 32;          // fp8 h buffer (n*128 bytes)
    unsigned* Wl1q = (unsigned*)p; p += 8192;      // MFMA-B-packed W_l1
    unsigned* Wl2q = (unsigned*)p; p += 8192;      // MFMA-B-packed W_l2
    unsigned* W1q  = (unsigned*)p; p += 7168;      // MFMA-B-packed mW1 (7 tiles)
    int* row_ptr     = (int*)p;
    int* gcursor     = row_ptr + n + 1;
    int* cnt         = gcursor + 256;
    float* W0s    = (float*)(cnt + 16);
    float* SA0    = W0s + HCONC;
    float* SD0    = SA0 + NHEAD;
    float* meanat = SD0 + NHEAD;     // unused (kept for layout stability)
    float* stab   = meanat + EDIM;   // 3*68 = 204, round to 256
    char* raw = (char*)(stab + 256);
    unsigned* ebuf = (unsigned*)(((uintptr_t)raw + 15) & ~(uintptr_t)15); // nbuk*BCAP u32
    unsigned* col = ebuf + (size_t)nbuk * BCAP;                          // E entries

    // CSR build: memset cursors -> binA (binning + weight pack + setup riding
    // along) -> binB (fine sort + fused layer-0 -> val0 only)
    hipMemsetAsync(gcursor, 0, (256 + 16) * sizeof(int), stream);
    binA_kernel<<<nA + 93, 256, 0, stream>>>(ei, etype, E, nbuk, nA, gcursor, cnt,
                                             ebuf, W_l1, W_l2, mW1, Wl1q, Wl2q, W1q,
                                             W_l0, emb, att_src, att_dst, att_edge,
                                             W_edge, W0s, SA0, SD0, stab);
    binB_kernel<<<nbuk, 256, 0, stream>>>(ebuf, gcursor, n, nbuk, row_ptr, col,
                                          cnt, stab, E, x, SA0, SD0, val0);

    // layer 1: transform reconstructs rows from val0 (no xa materialization);
    // agg1 emits bf16 rows (xb)
    transform0_kernel<<<(n + 63) / 64, 256, 0, stream>>>(val0, W0s, bias + 0, Wl1q,
                                                         att_src + 128, att_dst + 128,
                                                         (unsigned short*)hbf, ssrc, sdst, n);
    agg_kernel<true, true, false><<<(n + 15) / 16, 256, 0, stream>>>(
        (const unsigned char*)hbf, ssrc, sdst, row_ptr, col,
        stab + 68, bias + 128, nullptr, val0, W0s, bias + 0, xb, n);
    // layer 2: transform reads bf16 rows; agg2 residual from bf16 xb; bf16 out
    transform_kernel<<<(n + 63) / 64, 256, 0, stream>>>((const unsigned short*)xb, Wl2q,
                                                        att_src + 256, att_dst + 256,
                                                        (unsigned short*)hbf, ssrc, sdst, n);
    agg_kernel<false, true, true><<<(n + 15) / 16, 256, 0, stream>>>(
        (const unsigned char*)hbf, ssrc, sdst, row_ptr, col,
        stab + 136, bias + 256, xb, nullptr, nullptr, nullptr, xa, n);
    // MLP head (MFMA, bf16 input)
    mlp_kernel<<<(n + 63) / 64, 256, 0, stream>>>((const unsigned short*)xa, W1q,
                                                  mb1, mW2, mb2, (float*)d_out, n);
}

// Round 7
// 202.687 us; speedup vs baseline: 1.2914x; 1.0873x over previous
//
#include <hip/hip_runtime.h>
#include <hip/hip_bf16.h>
#include <hip/hip_fp16.h>

#define HCONC 128   // H*C
#define NHEAD 4
#define CCH   32
#define EDIM  8
#define NREL  16
#define BCAP  5120  // per-bucket capacity (mean ~4081, +16 sigma headroom)
#define TILE  2048  // edges per binA block

typedef float floatx2 __attribute__((ext_vector_type(2)));
typedef short bf16x8 __attribute__((ext_vector_type(8)));
typedef float f32x4 __attribute__((ext_vector_type(4)));

__device__ inline unsigned short pack_fp8x2(float a, float b) {
    return (unsigned short)(__builtin_amdgcn_cvt_pk_fp8_f32(a, b, 0, false) & 0xFFFF);
}
__device__ inline unsigned pack_bf2(float lo, float hi) {
    __hip_bfloat162 v;
    v.x = __float2bfloat16(lo);
    v.y = __float2bfloat16(hi);
    return *(unsigned*)&v;
}

// ---------------------------------------------------------------------------
// binA: tile-local counting sort by dst-bucket, coalesced run writes.
// Blocks [nA, nA+92): MFMA weight packing.  Block nA+92: setup.
// Cursors are RELATIVE (zero-initialized by a tiny memset before launch).
// ebuf record: src(16) | typ(4)<<16 | (dst&255)<<20  -- bucket implicit.
__global__ __launch_bounds__(256) void binA_kernel(
    const int* __restrict__ ei, const int* __restrict__ etype, int E, int nbuk, int nA,
    int* __restrict__ gcursor, int* __restrict__ cnt, unsigned* __restrict__ ebuf,
    const float* __restrict__ W_l1, const float* __restrict__ W_l2,
    const float* __restrict__ mW1,
    unsigned* __restrict__ Wl1q, unsigned* __restrict__ Wl2q, unsigned* __restrict__ W1q,
    const float* __restrict__ W_l0, const float* __restrict__ emb,
    const float* __restrict__ att_src, const float* __restrict__ att_dst,
    const float* __restrict__ att_edge, const float* __restrict__ W_edge,
    float* __restrict__ W0s, float* __restrict__ SA0, float* __restrict__ SD0,
    float* __restrict__ stab) {
    __shared__ int hist[256], lbase[256], gbase[256], tmp[256];
    __shared__ int lcnt16[NREL];
    __shared__ unsigned srt[TILE];
    __shared__ unsigned char sbuk[TILE];
    __shared__ float W0s_s[HCONC];
    int t = threadIdx.x;

    if ((int)blockIdx.x >= nA) {               // ---- pack / setup blocks ----
        int pb = (int)blockIdx.x - nA;
        if (pb == 92) {                        // setup (weights only; no cnt dep)
            if (t < HCONC) {
                float s = 0.f;
                for (int k = 0; k < CCH; k++) s += W_l0[k * HCONC + t];
                W0s[t] = s; W0s_s[t] = s;
            }
            __syncthreads();
            if (t < NHEAD) {
                float sa = 0.f, sd = 0.f;
                for (int c = 0; c < CCH; c++) {
                    sa += W0s_s[t * CCH + c] * att_src[t * CCH + c];
                    sd += W0s_s[t * CCH + c] * att_dst[t * CCH + c];
                }
                SA0[t] = sa; SD0[t] = sd;
            }
            if (t < 192) {                     // 3 layers x 16 types x 4 heads
                int l = t >> 6, rem = t & 63, typ = rem >> 2, hh = rem & 3;
                const float* attr = emb + typ * EDIM;
                const float* We = W_edge + l * EDIM * HCONC;
                const float* ae = att_edge + l * HCONC + hh * CCH;
                float s = 0.f;
                for (int c = 0; c < CCH; c++) {
                    float ev = 0.f;
                    for (int dd = 0; dd < EDIM; dd++)
                        ev += attr[dd] * We[dd * HCONC + hh * CCH + c];
                    s += ev * ae[c];
                }
                stab[l * 68 + typ * 4 + hh] = s;   // mean entries filled by binB b==0
            }
            return;
        }
        int i = pb * 256 + t;
        if (i < 16384) {                       // MFMA B-pack (W_l1 then W_l2)
            const float* W = (i < 8192) ? W_l1 : W_l2;
            unsigned* dst = (i < 8192) ? Wl1q : Wl2q;
            int r = i & 8191;
            int j2 = r & 3, lane = (r >> 2) & 63, kb = (r >> 8) & 3, tt = r >> 10;
            int k0 = kb * 32 + ((lane >> 4) & 3) * 8 + 2 * j2;
            int c = 16 * tt + (lane & 15);
            dst[r] = pack_bf2(W[k0 * 128 + c], W[(k0 + 1) * 128 + c]);
        } else if (i < 16384 + 7168) {         // mlp W1 B-pack, 7 tiles
            int r = i - 16384;
            int j2 = r & 3, lane = (r >> 2) & 63, kb = (r >> 8) & 3, tt = r >> 10;
            int k0 = kb * 32 + ((lane >> 4) & 3) * 8 + 2 * j2;
            int c = 16 * tt + (lane & 15);
            float lo = (c < 100) ? mW1[k0 * 100 + c] : 0.f;
            float hi = (c < 100) ? mW1[(k0 + 1) * 100 + c] : 0.f;
            W1q[r] = pack_bf2(lo, hi);
        }
        return;
    }

    // ---- edge binning ----
    hist[t] = 0;
    if (t < NREL) lcnt16[t] = 0;
    __syncthreads();

    int base = blockIdx.x * TILE;
    int count = min(TILE, E - base);

    unsigned rec[8]; int slot[8]; int buk[8];
#pragma unroll
    for (int i = 0; i < 8; i++) {
        int idx = t + i * 256;
        if (idx < count) {
            int g = base + idx;
            int s = ei[g], d = ei[E + g], ty = etype[g];
            rec[i] = (unsigned)s | ((unsigned)ty << 16) | ((unsigned)(d & 255) << 20);
            buk[i] = d >> 8;
            slot[i] = atomicAdd(&hist[buk[i]], 1);
            atomicAdd(&lcnt16[ty], 1);
        } else buk[i] = -1;
    }
    __syncthreads();

    int v = hist[t];
    tmp[t] = v; __syncthreads();
    for (int off = 1; off < 256; off <<= 1) {
        int add = (t >= off) ? tmp[t - off] : 0; __syncthreads();
        tmp[t] += add; __syncthreads();
    }
    lbase[t] = tmp[t] - v;
    if (t < nbuk && v > 0) gbase[t] = atomicAdd(&gcursor[t], v);  // relative reserve
    __syncthreads();

#pragma unroll
    for (int i = 0; i < 8; i++)
        if (buk[i] >= 0) {
            int pos = lbase[buk[i]] + slot[i];
            srt[pos] = rec[i];
            sbuk[pos] = (unsigned char)buk[i];
        }
    if (t < NREL) atomicAdd(&cnt[t], lcnt16[t]);
    __syncthreads();

    for (int idx = t; idx < count; idx += 256) {
        unsigned r = srt[idx];
        int bk = sbuk[idx];
        int rel = gbase[bk] + idx - lbase[bk];
        if (rel < BCAP) ebuf[bk * BCAP + rel] = r;   // cap guard (never trips)
    }
}

// ---------------------------------------------------------------------------
// binB: per-bucket fine sort + FUSED layer-0 aggregation -> val0[n][4] only
// (rank-1 layer-0 output; consumers reconstruct rows on the fly).
__global__ __launch_bounds__(256) void binB_kernel(
    const unsigned* __restrict__ ebuf, const int* __restrict__ gcursor,
    int n, int nbuk,
    int* __restrict__ row_ptr, unsigned* __restrict__ col,
    const int* __restrict__ cnt, float* __restrict__ stab, int E,
    const float* __restrict__ x,
    const float* __restrict__ SA0, const float* __restrict__ SD0,
    float* __restrict__ val0) {
    __shared__ int hist[256], lcur[256], tmp[256];
    __shared__ unsigned colsl[BCAP];            // 20 KB
    __shared__ __align__(16) float stab0[68];
    int b = blockIdx.x, t = threadIdx.x;

    if (t < 64) stab0[t] = stab[t];             // layer-0 per-type entries
    float invE = 1.f / (float)E;
    if (t < 4) {                                // local layer-0 mean entry
        float s = 0.f;
        for (int r = 0; r < NREL; r++) s += (float)cnt[r] * stab[r * 4 + t];
        stab0[64 + t] = s * invE;
    }

    // inline bucket-base scan (gcursor holds per-bucket sizes)
    int c = (t < nbuk) ? gcursor[t] : 0;
    tmp[t] = c; __syncthreads();
    for (int off = 1; off < 256; off <<= 1) {
        int add = (t >= off) ? tmp[t - off] : 0; __syncthreads();
        tmp[t] += add; __syncthreads();
    }
    int gstart = (b == 0) ? 0 : tmp[b - 1];
    if (b == 0 && t == nbuk - 1) row_ptr[n] = tmp[t];   // total edge count
    if (b == 0 && t < 12) {                     // global mean entries, layers 0-2
        int l = t >> 2, hh = t & 3;
        float s = 0.f;
        for (int r = 0; r < NREL; r++) s += (float)cnt[r] * stab[l * 68 + r * 4 + hh];
        stab[l * 68 + 64 + hh] = s * invE;
    }
    __syncthreads();

    int bbase = b * BCAP;
    int cntb = min(gcursor[b], BCAP);
    hist[t] = 0;
    __syncthreads();
    for (int i = t; i < cntb; i += 256) {
        unsigned r = ebuf[bbase + i];
        atomicAdd(&hist[r >> 20], 1);
    }
    __syncthreads();
    int v = hist[t];
    tmp[t] = v; __syncthreads();
    for (int off = 1; off < 256; off <<= 1) {
        int add = (t >= off) ? tmp[t - off] : 0; __syncthreads();
        tmp[t] += add; __syncthreads();
    }
    lcur[t] = tmp[t] - v;
    int gdst = (b << 8) + t;
    if (gdst < n) row_ptr[gdst] = gstart + tmp[t] - v;
    __syncthreads();
    for (int i = t; i < cntb; i += 256) {
        unsigned r = ebuf[bbase + i];
        int pos = atomicAdd(&lcur[r >> 20], 1);
        colsl[pos] = r & 0xFFFFFu;              // src | typ<<16
    }
    __syncthreads();
    for (int i = t; i < cntb; i += 256)
        col[gstart + i] = colsl[i];

    // ---- fused layer-0 aggregation (h0 is rank-1: per-(dst,head) scalar) ----
    int lo = tmp[t] - v, hi = tmp[t];           // this dst's range in colsl
    if (gdst < n) {
        float xd = x[gdst];
        float4 sa4 = *(const float4*)SA0;
        float4 sdc = *(const float4*)SD0;
        float sd0 = xd * sdc.x, sd1 = xd * sdc.y, sd2 = xd * sdc.z, sd3 = xd * sdc.w;
        // self edge (typ=16 -> mean attr)
        float s0 = fmaf(xd, sa4.x, sd0) + stab0[64];
        float s1 = fmaf(xd, sa4.y, sd1) + stab0[65];
        float s2 = fmaf(xd, sa4.z, sd2) + stab0[66];
        float s3 = fmaf(xd, sa4.w, sd3) + stab0[67];
        s0 = s0 > 0.f ? s0 : 0.2f * s0;
        s1 = s1 > 0.f ? s1 : 0.2f * s1;
        s2 = s2 > 0.f ? s2 : 0.2f * s2;
        s3 = s3 > 0.f ? s3 : 0.2f * s3;
        float w0 = __expf(s0), w1 = __expf(s1), w2 = __expf(s2), w3 = __expf(s3);
        float den0 = w0, den1 = w1, den2 = w2, den3 = w3;
        float sx0 = w0 * xd, sx1 = w1 * xd, sx2 = w2 * xd, sx3 = w3 * xd;
        for (int j = lo; j < hi; j++) {
            unsigned p = colsl[j];
            float xv = x[p & 0xFFFFu];
            int typ = (int)(p >> 16);
            float4 st = *(const float4*)&stab0[typ * 4];
            float e0 = fmaf(xv, sa4.x, sd0) + st.x;
            float e1 = fmaf(xv, sa4.y, sd1) + st.y;
            float e2 = fmaf(xv, sa4.z, sd2) + st.z;
            float e3 = fmaf(xv, sa4.w, sd3) + st.w;
            e0 = e0 > 0.f ? e0 : 0.2f * e0;
            e1 = e1 > 0.f ? e1 : 0.2f * e1;
            e2 = e2 > 0.f ? e2 : 0.2f * e2;
            e3 = e3 > 0.f ? e3 : 0.2f * e3;
            float g0 = __expf(e0), g1 = __expf(e1), g2 = __expf(e2), g3 = __expf(e3);
            den0 += g0; den1 += g1; den2 += g2; den3 += g3;
            sx0 = fmaf(g0, xv, sx0); sx1 = fmaf(g1, xv, sx1);
            sx2 = fmaf(g2, xv, sx2); sx3 = fmaf(g3, xv, sx3);
        }
        float4 vo;
        vo.x = sx0 / (den0 + 1e-16f);
        vo.y = sx1 / (den1 + 1e-16f);
        vo.z = sx2 / (den2 + 1e-16f);
        vo.w = sx3 / (den3 + 1e-16f);
        ((float4*)val0)[gdst] = vo;
    }
}

// ---------------------------------------------------------------------------
// Layer-1 transform: A rows reconstructed in-register from val0 (rank-1 layer-0
// output), B = MFMA-packed W_l1.  Bit-identical to reading the materialized xa.
__global__ __launch_bounds__(256, 2) void transform0_kernel(
    const float* __restrict__ val0, const float* __restrict__ W0s,
    const float* __restrict__ bias0, const unsigned* __restrict__ Wq,
    const float* __restrict__ a_src, const float* __restrict__ a_dst,
    unsigned short* __restrict__ h8, float* __restrict__ s_src,
    float* __restrict__ s_dst, int n) {
    __shared__ unsigned short hs[64 * 128];   // 16 KB epilogue transpose
    int tid = threadIdx.x;
    int lane = tid & 63;
    int wv = tid >> 6;
    int q = lane >> 4, nl = lane & 15;
    int row_blk = blockIdx.x * 64;
    int wrow = wv * 16;

    int arow = row_blk + wrow + nl;
    if (arow >= n) arow = n - 1;              // clamp; stores are guarded
    float4 v4 = ((const float4*)val0)[arow];

    f32x4 acc[8];
#pragma unroll
    for (int t = 0; t < 8; t++) acc[t] = (f32x4){0.f, 0.f, 0.f, 0.f};

    const uint4* Wp4 = (const uint4*)Wq;
#pragma unroll
    for (int kb = 0; kb < 4; kb++) {
        int c4 = 8 * kb + 2 * q;              // float4 index of channel block
        float4 wa = ((const float4*)W0s)[c4];
        float4 wb = ((const float4*)W0s)[c4 + 1];
        float4 ba = ((const float4*)bias0)[c4];
        float4 bb = ((const float4*)bias0)[c4 + 1];
        float vr = kb == 0 ? v4.x : kb == 1 ? v4.y : kb == 2 ? v4.z : v4.w;
        float x0 = fmaxf(fmaf(vr, wa.x, ba.x), 0.f);
        float x1 = fmaxf(fmaf(vr, wa.y, ba.y), 0.f);
        float x2 = fmaxf(fmaf(vr, wa.z, ba.z), 0.f);
        float x3 = fmaxf(fmaf(vr, wa.w, ba.w), 0.f);
        float x4 = fmaxf(fmaf(vr, wb.x, bb.x), 0.f);
        float x5 = fmaxf(fmaf(vr, wb.y, bb.y), 0.f);
        float x6 = fmaxf(fmaf(vr, wb.z, bb.z), 0.f);
        float x7 = fmaxf(fmaf(vr, wb.w, bb.w), 0.f);
        uint4 ua;
        ua.x = pack_bf2(x0, x1);
        ua.y = pack_bf2(x2, x3);
        ua.z = pack_bf2(x4, x5);
        ua.w = pack_bf2(x6, x7);
        bf16x8 af = __builtin_bit_cast(bf16x8, ua);
#pragma unroll
        for (int t = 0; t < 8; t++) {
            uint4 ub = Wp4[(t * 4 + kb) * 64 + lane];
            bf16x8 bf = __builtin_bit_cast(bf16x8, ub);
            acc[t] = __builtin_amdgcn_mfma_f32_16x16x32_bf16(af, bf, acc[t], 0, 0, 0);
        }
    }

    // scores: lane holds col c=16t+nl of rows wrow+q*4+reg
    float av[8], dv[8];
#pragma unroll
    for (int t = 0; t < 8; t++) {
        av[t] = a_src[16 * t + nl];
        dv[t] = a_dst[16 * t + nl];
    }
#pragma unroll
    for (int reg = 0; reg < 4; reg++) {
        float t0 = acc[0][reg] * av[0] + acc[1][reg] * av[1];
        float t1 = acc[2][reg] * av[2] + acc[3][reg] * av[3];
        float t2 = acc[4][reg] * av[4] + acc[5][reg] * av[5];
        float t3 = acc[6][reg] * av[6] + acc[7][reg] * av[7];
        float d0 = acc[0][reg] * dv[0] + acc[1][reg] * dv[1];
        float d1 = acc[2][reg] * dv[2] + acc[3][reg] * dv[3];
        float d2 = acc[4][reg] * dv[4] + acc[5][reg] * dv[5];
        float d3 = acc[6][reg] * dv[6] + acc[7][reg] * dv[7];
#pragma unroll
        for (int off = 1; off <= 8; off <<= 1) {
            t0 += __shfl_xor(t0, off); t1 += __shfl_xor(t1, off);
            t2 += __shfl_xor(t2, off); t3 += __shfl_xor(t3, off);
            d0 += __shfl_xor(d0, off); d1 += __shfl_xor(d1, off);
            d2 += __shfl_xor(d2, off); d3 += __shfl_xor(d3, off);
        }
        int row = row_blk + wrow + q * 4 + reg;
        if (row < n && nl < 4) {
            float ts = nl == 0 ? t0 : nl == 1 ? t1 : nl == 2 ? t2 : t3;
            float td = nl == 0 ? d0 : nl == 1 ? d1 : nl == 2 ? d2 : d3;
            s_src[row * 4 + nl] = ts;
            s_dst[row * 4 + nl] = td;
        }
    }

    // h8: transpose acc through LDS (bf16) then pack fp8 coalesced
#pragma unroll
    for (int t = 0; t < 8; t++) {
#pragma unroll
        for (int reg = 0; reg < 4; reg++) {
            __hip_bfloat16 b = __float2bfloat16(acc[t][reg]);
            hs[(wrow + q * 4 + reg) * 128 + 16 * t + nl] = *(unsigned short*)&b;
        }
    }
    __syncthreads();
    const unsigned* hsu = (const unsigned*)hs;
#pragma unroll
    for (int i = 0; i < 16; i++) {
        int pidx = tid + i * 256;             // channel-pair index in 64x64
        int rl = pidx >> 6, cp = pidx & 63;
        int row = row_blk + rl;
        if (row < n) {
            unsigned u = hsu[rl * 64 + cp];
            float f0 = __uint_as_float(u << 16);
            float f1 = __uint_as_float(u & 0xFFFF0000u);
            h8[(size_t)row * 64 + cp] = pack_fp8x2(f0, f1);
        }
    }
}

// ---------------------------------------------------------------------------
// agg1 + fused layer-2 transform.  Each block owns 16 dsts = one 16-row MFMA
// A-tile.  After the gather loop the block's rows are staged in LDS; wave wv
// handles col-tiles {2wv,2wv+1} = head wv (scores reduce entirely in-wave),
// then all 256 threads repack h2 to fp8.  Outputs go to SECOND h8/s buffers
// (layer-1 buffers are still being read by other blocks -> no race).
__global__ __launch_bounds__(256) void agg_t_kernel(
    const unsigned char* __restrict__ h8, const float* __restrict__ s_src,
    const float* __restrict__ s_dst, const int* __restrict__ row_ptr,
    const unsigned* __restrict__ col, const float* __restrict__ tab,
    const float* __restrict__ bias, const float* __restrict__ val0,
    const float* __restrict__ W0s, const float* __restrict__ bias0,
    unsigned short* __restrict__ xb_out,      // bf16 rows (residual for agg_m)
    const unsigned* __restrict__ Wq,          // Wl2q
    const float* __restrict__ a_src2, const float* __restrict__ a_dst2,
    unsigned short* __restrict__ h8o, float* __restrict__ s_srco,
    float* __restrict__ s_dsto, int n) {
    __shared__ __align__(16) float stab_s[68];
    __shared__ __align__(16) unsigned short xrow[16 * 144];  // padded rows
    __shared__ __align__(4) unsigned short hs[16 * 130];
    if (threadIdx.x < 68) stab_s[threadIdx.x] = tab[threadIdx.x];
    __syncthreads();

    int tid = threadIdx.x;
    int lane = tid & 63;
    int wv = tid >> 6;
    int grp = lane >> 4;              // == MFMA q
    int l16 = lane & 15;              // == MFMA nl
    int head = l16 >> 2;
    int dl = wv * 4 + grp;            // local row 0..15
    int d = blockIdx.x * 16 + dl;
    bool alive = d < n;
    int dc = alive ? d : n - 1;

    int start = row_ptr[dc];
    int end = alive ? row_ptr[dc + 1] : start;
    float sdh = s_dst[dc * 4 + head];

    // ---- gather main loop (v3) ----
    float s = s_src[dc * 4 + head] + sdh + stab_s[64 + head];
    s = s > 0.f ? s : 0.2f * s;
    float w = __expf(s);
    uint2 u = ((const uint2*)(h8 + (size_t)dc * 128))[l16];
    floatx2 f01 = __builtin_amdgcn_cvt_pk_f32_fp8((int)u.x, false);
    floatx2 f23 = __builtin_amdgcn_cvt_pk_f32_fp8((int)u.x, true);
    floatx2 f45 = __builtin_amdgcn_cvt_pk_f32_fp8((int)u.y, false);
    floatx2 f67 = __builtin_amdgcn_cvt_pk_f32_fp8((int)u.y, true);
    float den = w;
    float a0 = w * f01.x, a1 = w * f01.y;
    float a2 = w * f23.x, a3 = w * f23.y;
    float a4 = w * f45.x, a5 = w * f45.y;
    float a6 = w * f67.x, a7 = w * f67.y;
#pragma unroll 4
    for (int e = start; e < end; e++) {
        unsigned pp = col[e];
        int esrc = (int)(pp & 0xFFFFu);
        int typ = (int)(pp >> 16);
        float sc = s_src[esrc * 4 + head] + sdh + stab_s[typ * 4 + head];
        sc = sc > 0.f ? sc : 0.2f * sc;
        float we = __expf(sc);
        uint2 ue = ((const uint2*)(h8 + (size_t)esrc * 128))[l16];
        floatx2 g01 = __builtin_amdgcn_cvt_pk_f32_fp8((int)ue.x, false);
        floatx2 g23 = __builtin_amdgcn_cvt_pk_f32_fp8((int)ue.x, true);
        floatx2 g45 = __builtin_amdgcn_cvt_pk_f32_fp8((int)ue.y, false);
        floatx2 g67 = __builtin_amdgcn_cvt_pk_f32_fp8((int)ue.y, true);
        den += we;
        a0 = fmaf(we, g01.x, a0);  a1 = fmaf(we, g01.y, a1);
        a2 = fmaf(we, g23.x, a2);  a3 = fmaf(we, g23.y, a3);
        a4 = fmaf(we, g45.x, a4);  a5 = fmaf(we, g45.y, a5);
        a6 = fmaf(we, g67.x, a6);  a7 = fmaf(we, g67.y, a7);
    }

    // ---- row epilogue: bias + val0 residual + relu -> bf16 ----
    float inv = 1.f / (den + 1e-16f);
    float4 b0 = ((const float4*)bias)[2 * l16];
    float4 b1v = ((const float4*)bias)[2 * l16 + 1];
    float4 o0v, o1v;
    o0v.x = a0 * inv + b0.x;  o0v.y = a1 * inv + b0.y;
    o0v.z = a2 * inv + b0.z;  o0v.w = a3 * inv + b0.w;
    o1v.x = a4 * inv + b1v.x; o1v.y = a5 * inv + b1v.y;
    o1v.z = a6 * inv + b1v.z; o1v.w = a7 * inv + b1v.w;
    {   // residual = relu(val0[d][head]*W0s[c]+bias0[c])
        float vv = val0[dc * 4 + head];
        float4 wa = ((const float4*)W0s)[2 * l16];
        float4 wb = ((const float4*)W0s)[2 * l16 + 1];
        float4 ba = ((const float4*)bias0)[2 * l16];
        float4 bb = ((const float4*)bias0)[2 * l16 + 1];
        o0v.x += fmaxf(fmaf(vv, wa.x, ba.x), 0.f);
        o0v.y += fmaxf(fmaf(vv, wa.y, ba.y), 0.f);
        o0v.z += fmaxf(fmaf(vv, wa.z, ba.z), 0.f);
        o0v.w += fmaxf(fmaf(vv, wa.w, ba.w), 0.f);
        o1v.x += fmaxf(fmaf(vv, wb.x, bb.x), 0.f);
        o1v.y += fmaxf(fmaf(vv, wb.y, bb.y), 0.f);
        o1v.z += fmaxf(fmaf(vv, wb.z, bb.z), 0.f);
        o1v.w += fmaxf(fmaf(vv, wb.w, bb.w), 0.f);
    }
    o0v.x = fmaxf(o0v.x, 0.f); o0v.y = fmaxf(o0v.y, 0.f);
    o0v.z = fmaxf(o0v.z, 0.f); o0v.w = fmaxf(o0v.w, 0.f);
    o1v.x = fmaxf(o1v.x, 0.f); o1v.y = fmaxf(o1v.y, 0.f);
    o1v.z = fmaxf(o1v.z, 0.f); o1v.w = fmaxf(o1v.w, 0.f);
    uint4 pk;
    pk.x = pack_bf2(o0v.x, o0v.y);
    pk.y = pack_bf2(o0v.z, o0v.w);
    pk.z = pack_bf2(o1v.x, o1v.y);
    pk.w = pack_bf2(o1v.z, o1v.w);
    if (alive) ((uint4*)xb_out)[(size_t)d * 16 + l16] = pk;   // residual copy
    *(uint4*)&xrow[dl * 144 + l16 * 8] = pk;                  // MFMA A-tile
    __syncthreads();

    // ---- fused transform: wave wv = col-tiles {2wv,2wv+1} = head wv ----
    int lo = 2 * wv, hi = lo + 1;
    f32x4 aL = (f32x4){0.f, 0.f, 0.f, 0.f};
    f32x4 aH = (f32x4){0.f, 0.f, 0.f, 0.f};
    const uint4* Wp4 = (const uint4*)Wq;
#pragma unroll
    for (int kb = 0; kb < 4; kb++) {
        bf16x8 af = __builtin_bit_cast(bf16x8,
            *(const uint4*)&xrow[l16 * 144 + kb * 32 + grp * 8]);
        bf16x8 bL = __builtin_bit_cast(bf16x8, Wp4[(lo * 4 + kb) * 64 + lane]);
        bf16x8 bH = __builtin_bit_cast(bf16x8, Wp4[(hi * 4 + kb) * 64 + lane]);
        aL = __builtin_amdgcn_mfma_f32_16x16x32_bf16(af, bL, aL, 0, 0, 0);
        aH = __builtin_amdgcn_mfma_f32_16x16x32_bf16(af, bH, aH, 0, 0, 0);
    }
    float avl = a_src2[32 * wv + l16], avh = a_src2[32 * wv + 16 + l16];
    float dvl = a_dst2[32 * wv + l16], dvh = a_dst2[32 * wv + 16 + l16];
#pragma unroll
    for (int reg = 0; reg < 4; reg++) {
        float ps = aL[reg] * avl + aH[reg] * avh;
        float pd = aL[reg] * dvl + aH[reg] * dvh;
#pragma unroll
        for (int off = 1; off <= 8; off <<= 1) {
            ps += __shfl_xor(ps, off);
            pd += __shfl_xor(pd, off);
        }
        int rg = blockIdx.x * 16 + grp * 4 + reg;
        if (l16 == 0 && rg < n) {
            s_srco[rg * 4 + wv] = ps;
            s_dsto[rg * 4 + wv] = pd;
        }
        __hip_bfloat16 bLh = __float2bfloat16(aL[reg]);
        __hip_bfloat16 bHh = __float2bfloat16(aH[reg]);
        hs[(grp * 4 + reg) * 130 + 16 * lo + l16] = *(unsigned short*)&bLh;
        hs[(grp * 4 + reg) * 130 + 16 * hi + l16] = *(unsigned short*)&bHh;
    }
    __syncthreads();
#pragma unroll
    for (int i = 0; i < 4; i++) {
        int pidx = tid + i * 256;             // 16 rows x 64 channel-pairs
        int rl = pidx >> 6, cp = pidx & 63;
        int rg = blockIdx.x * 16 + rl;
        if (rg < n) {
            unsigned uu = *(const unsigned*)&hs[rl * 130 + cp * 2];
            float f0 = __uint_as_float(uu << 16);
            float f1 = __uint_as_float(uu & 0xFFFF0000u);
            h8o[(size_t)rg * 64 + cp] = pack_fp8x2(f0, f1);
        }
    }
}

// ---------------------------------------------------------------------------
// agg2 + fused MLP head.  Same 16-row block structure; residual from bf16 xb;
// waves 0-2 take mlp col-tiles {2wv,2wv+1}, wave 3 takes tile 6; partials
// combine through LDS; 16 threads apply sigmoid and store.
__global__ __launch_bounds__(256) void agg_m_kernel(
    const unsigned char* __restrict__ h8, const float* __restrict__ s_src,
    const float* __restrict__ s_dst, const int* __restrict__ row_ptr,
    const unsigned* __restrict__ col, const float* __restrict__ tab,
    const float* __restrict__ bias, const unsigned short* __restrict__ x_prev,
    const unsigned* __restrict__ W1q, const float* __restrict__ b1,
    const float* __restrict__ W2, const float* __restrict__ b2,
    float* __restrict__ out, int n) {
    __shared__ __align__(16) float stab_s[68];
    __shared__ __align__(16) unsigned short xrow[16 * 144];
    __shared__ float partial[16][4];
    if (threadIdx.x < 68) stab_s[threadIdx.x] = tab[threadIdx.x];
    __syncthreads();

    int tid = threadIdx.x;
    int lane = tid & 63;
    int wv = tid >> 6;
    int grp = lane >> 4;
    int l16 = lane & 15;
    int head = l16 >> 2;
    int dl = wv * 4 + grp;
    int d = blockIdx.x * 16 + dl;
    bool alive = d < n;
    int dc = alive ? d : n - 1;

    int start = row_ptr[dc];
    int end = alive ? row_ptr[dc + 1] : start;
    float sdh = s_dst[dc * 4 + head];

    float s = s_src[dc * 4 + head] + sdh + stab_s[64 + head];
    s = s > 0.f ? s : 0.2f * s;
    float w = __expf(s);
    uint2 u = ((const uint2*)(h8 + (size_t)dc * 128))[l16];
    floatx2 f01 = __builtin_amdgcn_cvt_pk_f32_fp8((int)u.x, false);
    floatx2 f23 = __builtin_amdgcn_cvt_pk_f32_fp8((int)u.x, true);
    floatx2 f45 = __builtin_amdgcn_cvt_pk_f32_fp8((int)u.y, false);
    floatx2 f67 = __builtin_amdgcn_cvt_pk_f32_fp8((int)u.y, true);
    float den = w;
    float a0 = w * f01.x, a1 = w * f01.y;
    float a2 = w * f23.x, a3 = w * f23.y;
    float a4 = w * f45.x, a5 = w * f45.y;
    float a6 = w * f67.x, a7 = w * f67.y;
#pragma unroll 4
    for (int e = start; e < end; e++) {
        unsigned pp = col[e];
        int esrc = (int)(pp & 0xFFFFu);
        int typ = (int)(pp >> 16);
        float sc = s_src[esrc * 4 + head] + sdh + stab_s[typ * 4 + head];
        sc = sc > 0.f ? sc : 0.2f * sc;
        float we = __expf(sc);
        uint2 ue = ((const uint2*)(h8 + (size_t)esrc * 128))[l16];
        floatx2 g01 = __builtin_amdgcn_cvt_pk_f32_fp8((int)ue.x, false);
        floatx2 g23 = __builtin_amdgcn_cvt_pk_f32_fp8((int)ue.x, true);
        floatx2 g45 = __builtin_amdgcn_cvt_pk_f32_fp8((int)ue.y, false);
        floatx2 g67 = __builtin_amdgcn_cvt_pk_f32_fp8((int)ue.y, true);
        den += we;
        a0 = fmaf(we, g01.x, a0);  a1 = fmaf(we, g01.y, a1);
        a2 = fmaf(we, g23.x, a2);  a3 = fmaf(we, g23.y, a3);
        a4 = fmaf(we, g45.x, a4);  a5 = fmaf(we, g45.y, a5);
        a6 = fmaf(we, g67.x, a6);  a7 = fmaf(we, g67.y, a7);
    }

    float inv = 1.f / (den + 1e-16f);
    float4 b0 = ((const float4*)bias)[2 * l16];
    float4 b1v = ((const float4*)bias)[2 * l16 + 1];
    float4 o0v, o1v;
    o0v.x = a0 * inv + b0.x;  o0v.y = a1 * inv + b0.y;
    o0v.z = a2 * inv + b0.z;  o0v.w = a3 * inv + b0.w;
    o1v.x = a4 * inv + b1v.x; o1v.y = a5 * inv + b1v.y;
    o1v.z = a6 * inv + b1v.z; o1v.w = a7 * inv + b1v.w;
    {   // residual from bf16 xb
        uint4 pr = ((const uint4*)x_prev)[(size_t)dc * 16 + l16];
        o0v.x += __uint_as_float(pr.x << 16);
        o0v.y += __uint_as_float(pr.x & 0xFFFF0000u);
        o0v.z += __uint_as_float(pr.y << 16);
        o0v.w += __uint_as_float(pr.y & 0xFFFF0000u);
        o1v.x += __uint_as_float(pr.z << 16);
        o1v.y += __uint_as_float(pr.z & 0xFFFF0000u);
        o1v.z += __uint_as_float(pr.w << 16);
        o1v.w += __uint_as_float(pr.w & 0xFFFF0000u);
    }
    o0v.x = fmaxf(o0v.x, 0.f); o0v.y = fmaxf(o0v.y, 0.f);
    o0v.z = fmaxf(o0v.z, 0.f); o0v.w = fmaxf(o0v.w, 0.f);
    o1v.x = fmaxf(o1v.x, 0.f); o1v.y = fmaxf(o1v.y, 0.f);
    o1v.z = fmaxf(o1v.z, 0.f); o1v.w = fmaxf(o1v.w, 0.f);
    uint4 pk;
    pk.x = pack_bf2(o0v.x, o0v.y);
    pk.y = pack_bf2(o0v.z, o0v.w);
    pk.z = pack_bf2(o1v.x, o1v.y);
    pk.w = pack_bf2(o1v.z, o1v.w);
    *(uint4*)&xrow[dl * 144 + l16 * 8] = pk;   // no global xa write at all
    __syncthreads();

    // ---- fused MLP: waves 0-2 tiles {2wv,2wv+1}, wave 3 tile 6 ----
    int lo = 2 * wv;
    bool two = wv < 3;
    f32x4 aL = (f32x4){0.f, 0.f, 0.f, 0.f};
    f32x4 aH = (f32x4){0.f, 0.f, 0.f, 0.f};
    const uint4* Wp4 = (const uint4*)W1q;
#pragma unroll
    for (int kb = 0; kb < 4; kb++) {
        bf16x8 af = __builtin_bit_cast(bf16x8,
            *(const uint4*)&xrow[l16 * 144 + kb * 32 + grp * 8]);
        bf16x8 bL = __builtin_bit_cast(bf16x8, Wp4[(lo * 4 + kb) * 64 + lane]);
        aL = __builtin_amdgcn_mfma_f32_16x16x32_bf16(af, bL, aL, 0, 0, 0);
        if (two) {
            bf16x8 bH = __builtin_bit_cast(bf16x8, Wp4[((lo + 1) * 4 + kb) * 64 + lane]);
            aH = __builtin_amdgcn_mfma_f32_16x16x32_bf16(af, bH, aH, 0, 0, 0);
        }
    }
    int cL = 16 * lo + l16;
    float b1L = (cL < 100) ? b1[cL] : 0.f;
    float w2L = (cL < 100) ? W2[cL] : 0.f;
    float b1H = 0.f, w2H = 0.f;
    if (two) {
        int cH = cL + 16;
        b1H = (cH < 100) ? b1[cH] : 0.f;
        w2H = (cH < 100) ? W2[cH] : 0.f;
    }
#pragma unroll
    for (int reg = 0; reg < 4; reg++) {
        float psum = fmaxf(aL[reg] + b1L, 0.f) * w2L;
        if (two) psum = fmaf(fmaxf(aH[reg] + b1H, 0.f), w2H, psum);
#pragma unroll
        for (int off = 1; off <= 8; off <<= 1)
            psum += __shfl_xor(psum, off);
        if (l16 == 0) partial[grp * 4 + reg][wv] = psum;
    }
    __syncthreads();
    if (tid < 16) {
        int rg = blockIdx.x * 16 + tid;
        if (rg < n) {
            float sum = partial[tid][0] + partial[tid][1] +
                        partial[tid][2] + partial[tid][3] + b2[0];
            out[rg] = 1.f / (1.f + __expf(-sum));
        }
    }
}

// ---------------------------------------------------------------------------
extern "C" void kernel_launch(void* const* d_in, const int* in_sizes, int n_in,
                              void* d_out, int out_size, void* d_ws, size_t ws_size,
                              hipStream_t stream) {
    const float* x       = (const float*)d_in[0];
    const int*   ei      = (const int*)d_in[1];     // [2,E]: src then dst
    const int*   etype   = (const int*)d_in[2];
    const float* emb     = (const float*)d_in[3];   // [16,8]
    const float* W_l0    = (const float*)d_in[4];   // [32,128]
    const float* W_l1    = (const float*)d_in[5];   // [128,128]
    const float* W_l2    = (const float*)d_in[6];   // [128,128]
    const float* att_src = (const float*)d_in[7];   // [3,4,32]
    const float* att_dst = (const float*)d_in[8];
    const float* att_edge= (const float*)d_in[9];
    const float* W_edge  = (const float*)d_in[10];  // [3,8,128]
    const float* bias    = (const float*)d_in[11];  // [3,128]
    const float* mW1     = (const float*)d_in[12];  // [128,100]
    const float* mb1     = (const float*)d_in[13];
    const float* mW2     = (const float*)d_in[14];  // [100,1]
    const float* mb2     = (const float*)d_in[15];

    int n = in_sizes[0];   // 50000
    int E = in_sizes[2];   // 800000
    int nbuk = (n + 255) >> 8;   // 196
    int nA = (E + TILE - 1) / TILE;   // 391

    // workspace carve (keep 16-byte alignment for uint4 views)
    float* p   = (float*)d_ws;
    float* xb  = p; p += (size_t)n * 64;           // bf16 rows [n][128] = n*256 B
    float* ssrc = p; p += (size_t)n * NHEAD;       // layer-1 scores
    float* sdst = p; p += (size_t)n * NHEAD;
    float* ssrc2 = p; p += (size_t)n * NHEAD;      // layer-2 scores
    float* sdst2 = p; p += (size_t)n * NHEAD;
    float* val0 = p; p += (size_t)n * NHEAD;       // layer-0 rank-1 output
    float* hbf  = p; p += (size_t)n * 32;          // fp8 h buffer, layer 1
    float* hbf2 = p; p += (size_t)n * 32;          // fp8 h buffer, layer 2
    unsigned* Wl1q = (unsigned*)p; p += 8192;      // MFMA-B-packed W_l1
    unsigned* Wl2q = (unsigned*)p; p += 8192;      // MFMA-B-packed W_l2
    unsigned* W1q  = (unsigned*)p; p += 7168;      // MFMA-B-packed mW1 (7 tiles)
    int* row_ptr     = (int*)p;
    int* gcursor     = row_ptr + n + 1;
    int* cnt         = gcursor + 256;
    float* W0s    = (float*)(cnt + 16);
    float* SA0    = W0s + HCONC;
    float* SD0    = SA0 + NHEAD;
    float* meanat = SD0 + NHEAD;     // unused (kept for layout stability)
    float* stab   = meanat + EDIM;   // 3*68 = 204, round to 256
    char* raw = (char*)(stab + 256);
    unsigned* ebuf = (unsigned*)(((uintptr_t)raw + 15) & ~(uintptr_t)15); // nbuk*BCAP u32
    unsigned* col = ebuf + (size_t)nbuk * BCAP;                          // E entries

    // CSR build: memset cursors -> binA (binning + weight pack + setup riding
    // along) -> binB (fine sort + fused layer-0 -> val0 only)
    (void)hipMemsetAsync(gcursor, 0, (256 + 16) * sizeof(int), stream);
    binA_kernel<<<nA + 93, 256, 0, stream>>>(ei, etype, E, nbuk, nA, gcursor, cnt,
                                             ebuf, W_l1, W_l2, mW1, Wl1q, Wl2q, W1q,
                                             W_l0, emb, att_src, att_dst, att_edge,
                                             W_edge, W0s, SA0, SD0, stab);
    binB_kernel<<<nbuk, 256, 0, stream>>>(ebuf, gcursor, n, nbuk, row_ptr, col,
                                          cnt, stab, E, x, SA0, SD0, val0);

    // layer 1 transform (from rank-1 val0)
    transform0_kernel<<<(n + 63) / 64, 256, 0, stream>>>(val0, W0s, bias + 0, Wl1q,
                                                         att_src + 128, att_dst + 128,
                                                         (unsigned short*)hbf, ssrc, sdst, n);
    // agg1 + fused layer-2 transform (writes xb residual + h8/s for layer 2)
    agg_t_kernel<<<(n + 15) / 16, 256, 0, stream>>>(
        (const unsigned char*)hbf, ssrc, sdst, row_ptr, col,
        stab + 68, bias + 128, val0, W0s, bias + 0,
        (unsigned short*)xb, Wl2q, att_src + 256, att_dst + 256,
        (unsigned short*)hbf2, ssrc2, sdst2, n);
    // agg2 + fused MLP head (no xa materialization)
    agg_m_kernel<<<(n + 15) / 16, 256, 0, stream>>>(
        (const unsigned char*)hbf2, ssrc2, sdst2, row_ptr, col,
        stab + 136, bias + 256, (const unsigned short*)xb,
        W1q, mb1, mW2, mb2, (float*)d_out, n);
}